// Round 1
// baseline (3272.555 us; speedup 1.0000x reference)
//
#include <hip/hip_runtime.h>
#include <hip/hip_bf16.h>
#include <math.h>

#define B_   32
#define NA   512
#define NP   1024
#define HID  256
#define NH   8
#define DH   32
#define PF   1024

// ---------------- feature transform: x = trg @ ft_w.T + ft_b ----------------
__global__ __launch_bounds__(256) void ft_kernel(const float* __restrict__ trg,
    const float* __restrict__ w, const float* __restrict__ b,
    float* __restrict__ out)
{
    __shared__ float Ws[256][35];
    int tid = threadIdx.x;
    for (int k = 0; k < 34; ++k) Ws[tid][k] = w[tid*34 + k];
    float bias = b[tid];
    __syncthreads();
    int m0 = blockIdx.x * 32;
    for (int r = 0; r < 32; ++r) {
        int m = m0 + r;
        const float* tr = trg + (size_t)m*34;
        float acc = bias;
        #pragma unroll
        for (int k = 0; k < 34; ++k) acc += tr[k] * Ws[tid][k];
        out[(size_t)m*HID + tid] = acc;
    }
}

// ---------------- GEMM: C[M,N] = A[M,K] @ W[N,K]^T + bias, optional relu ----
__global__ __launch_bounds__(256) void gemm_nt(const float* __restrict__ A,
    const float* __restrict__ W, const float* __restrict__ bias,
    float* __restrict__ C, int M, int N, int K, int relu)
{
    __shared__ float As[16][68];   // k-major, padded (272B rows: 16B aligned, 2-way banks max)
    __shared__ float Ws[16][68];
    int t  = threadIdx.x;
    int tx = t & 15, ty = t >> 4;
    int row0 = blockIdx.y * 64, col0 = blockIdx.x * 64;
    int lr = t >> 2, lc = (t & 3) * 4;
    const float* Ap = A + (size_t)(row0 + lr)*K + lc;
    const float* Wp = W + (size_t)(col0 + lr)*K + lc;
    float c[4][4] = {};
    for (int kt = 0; kt < K; kt += 16) {
        float4 av = *(const float4*)(Ap + kt);
        float4 wv = *(const float4*)(Wp + kt);
        __syncthreads();
        As[lc+0][lr] = av.x; As[lc+1][lr] = av.y; As[lc+2][lr] = av.z; As[lc+3][lr] = av.w;
        Ws[lc+0][lr] = wv.x; Ws[lc+1][lr] = wv.y; Ws[lc+2][lr] = wv.z; Ws[lc+3][lr] = wv.w;
        __syncthreads();
        #pragma unroll
        for (int kk = 0; kk < 16; ++kk) {
            float4 a = *(const float4*)&As[kk][ty*4];
            float4 w = *(const float4*)&Ws[kk][tx*4];
            c[0][0] += a.x*w.x; c[0][1] += a.x*w.y; c[0][2] += a.x*w.z; c[0][3] += a.x*w.w;
            c[1][0] += a.y*w.x; c[1][1] += a.y*w.y; c[1][2] += a.y*w.z; c[1][3] += a.y*w.w;
            c[2][0] += a.z*w.x; c[2][1] += a.z*w.y; c[2][2] += a.z*w.z; c[2][3] += a.z*w.w;
            c[3][0] += a.w*w.x; c[3][1] += a.w*w.y; c[3][2] += a.w*w.z; c[3][3] += a.w*w.w;
        }
    }
    float4 bv = *(const float4*)(bias + col0 + tx*4);
    float bb[4] = {bv.x, bv.y, bv.z, bv.w};
    #pragma unroll
    for (int i = 0; i < 4; ++i) {
        float* cp = C + (size_t)(row0 + ty*4 + i)*N + col0 + tx*4;
        float4 o;
        o.x = c[i][0] + bb[0]; o.y = c[i][1] + bb[1];
        o.z = c[i][2] + bb[2]; o.w = c[i][3] + bb[3];
        if (relu) { o.x = fmaxf(o.x,0.f); o.y = fmaxf(o.y,0.f);
                    o.z = fmaxf(o.z,0.f); o.w = fmaxf(o.w,0.f); }
        *(float4*)cp = o;
    }
}

// ---------------- fused attention (flash-style, fp32) -----------------------
// grid: (Lq/64, NH, B). One block = 64 q-rows of one (b,h).
__global__ __launch_bounds__(256) void attn_kernel(const float* __restrict__ Q,
    const float* __restrict__ K, const float* __restrict__ V,
    float* __restrict__ O, int Lq, int Lk)
{
    __shared__ float Qs[64][36];
    __shared__ float Ks[64][36];
    __shared__ float Vs[64][36];
    __shared__ float S [64][68];
    int b = blockIdx.z, h = blockIdx.y, qt = blockIdx.x;
    int t = threadIdx.x;
    int qr = t >> 2, jg = t & 3;           // 64 rows x 4 thread-groups
    const float* Qb = Q + ((size_t)(b*Lq + qt*64))*HID + h*DH;
    const float* Kb = K + ((size_t)b*Lk)*HID + h*DH;
    const float* Vb = V + ((size_t)b*Lk)*HID + h*DH;

    {   // stage Q tile (64x32)
        int r = t >> 2, c = (t & 3) * 8;
        float4 v0 = *(const float4*)(Qb + (size_t)r*HID + c);
        float4 v1 = *(const float4*)(Qb + (size_t)r*HID + c + 4);
        *(float4*)&Qs[r][c]   = v0;
        *(float4*)&Qs[r][c+4] = v1;
    }
    __syncthreads();
    float4 qv[8];
    #pragma unroll
    for (int i = 0; i < 8; ++i) qv[i] = *(const float4*)&Qs[qr][i*4];

    float m = -1e30f, l = 0.f;
    float o[8] = {};
    const float scale = 0.17677669529663687f;  // 1/sqrt(32)

    for (int kt0 = 0; kt0 < Lk; kt0 += 64) {
        __syncthreads();
        {   // stage K,V tiles (64x32 each)
            int r = t >> 2, c = (t & 3) * 8;
            float4 k0 = *(const float4*)(Kb + (size_t)(kt0+r)*HID + c);
            float4 k1 = *(const float4*)(Kb + (size_t)(kt0+r)*HID + c + 4);
            float4 v0 = *(const float4*)(Vb + (size_t)(kt0+r)*HID + c);
            float4 v1 = *(const float4*)(Vb + (size_t)(kt0+r)*HID + c + 4);
            *(float4*)&Ks[r][c]   = k0; *(float4*)&Ks[r][c+4] = k1;
            *(float4*)&Vs[r][c]   = v0; *(float4*)&Vs[r][c+4] = v1;
        }
        __syncthreads();
        // scores: this thread does rows qr, cols j = 4*jj + jg
        #pragma unroll 4
        for (int jj = 0; jj < 16; ++jj) {
            int j = jj*4 + jg;
            float s = 0.f;
            #pragma unroll
            for (int kq = 0; kq < 8; ++kq) {
                float4 kv = *(const float4*)&Ks[j][kq*4];
                s += qv[kq].x*kv.x + qv[kq].y*kv.y + qv[kq].z*kv.z + qv[kq].w*kv.w;
            }
            S[qr][j] = s * scale;
        }
        __syncthreads();
        // online softmax + PV (each of 4 jg-threads handles 8 d-dims of row qr)
        float tm = -1e30f;
        #pragma unroll 8
        for (int j = 0; j < 64; ++j) tm = fmaxf(tm, S[qr][j]);
        float mn = fmaxf(m, tm);
        float corr = __expf(m - mn);
        l *= corr;
        #pragma unroll
        for (int d = 0; d < 8; ++d) o[d] *= corr;
        #pragma unroll 4
        for (int j = 0; j < 64; ++j) {
            float p = __expf(S[qr][j] - mn);
            l += p;
            float4 va = *(const float4*)&Vs[j][jg*8];
            float4 vb = *(const float4*)&Vs[j][jg*8+4];
            o[0] += p*va.x; o[1] += p*va.y; o[2] += p*va.z; o[3] += p*va.w;
            o[4] += p*vb.x; o[5] += p*vb.y; o[6] += p*vb.z; o[7] += p*vb.w;
        }
        m = mn;
    }
    float inv = 1.f / l;
    float* Ob = O + ((size_t)(b*Lq + qt*64 + qr))*HID + h*DH + jg*8;
    #pragma unroll
    for (int d = 0; d < 8; ++d) Ob[d] = o[d] * inv;
}

// ---------------- residual add + LayerNorm (in-place on x) -----------------
__global__ __launch_bounds__(256) void add_ln(float* __restrict__ x,
    const float* __restrict__ t, const float* __restrict__ g,
    const float* __restrict__ bt)
{
    __shared__ float red[256];
    int r = blockIdx.x, tid = threadIdx.x;
    size_t idx = (size_t)r*HID + tid;
    float v = x[idx] + t[idx];
    red[tid] = v; __syncthreads();
    for (int s = 128; s > 0; s >>= 1) { if (tid < s) red[tid] += red[tid+s]; __syncthreads(); }
    float mean = red[0] * (1.f/HID); __syncthreads();
    float d = v - mean;
    red[tid] = d*d; __syncthreads();
    for (int s = 128; s > 0; s >>= 1) { if (tid < s) red[tid] += red[tid+s]; __syncthreads(); }
    float var = red[0] * (1.f/HID);
    float rs = rsqrtf(var + 1e-5f);
    x[idx] = d * rs * g[tid] + bt[tid];
}

// ---------------- pooling + FC head ----------------------------------------
__global__ __launch_bounds__(256) void pool_head(const float* __restrict__ x,
    const float* __restrict__ fc1w, const float* __restrict__ fc1b,
    const float* __restrict__ fc2w, const float* __restrict__ fc2b,
    float* __restrict__ out)
{
    __shared__ float nw[512];
    __shared__ float p[256];
    __shared__ float a1[256];
    __shared__ float red[256];
    int b = blockIdx.x, tid = threadIdx.x;
    int wid = tid >> 6, lane = tid & 63;
    const float* xb = x + (size_t)b*NA*HID;
    for (int n = wid; n < NA; n += 4) {
        float s = 0.f;
        for (int hh = lane; hh < HID; hh += 64) { float vv = xb[(size_t)n*HID + hh]; s += vv*vv; }
        for (int off = 32; off > 0; off >>= 1) s += __shfl_down(s, off, 64);
        if (lane == 0) nw[n] = sqrtf(s);
    }
    __syncthreads();
    float v0 = nw[tid], v1 = nw[tid+256];
    red[tid] = fmaxf(v0, v1); __syncthreads();
    for (int s = 128; s > 0; s >>= 1) { if (tid < s) red[tid] = fmaxf(red[tid], red[tid+s]); __syncthreads(); }
    float mx = red[0]; __syncthreads();
    float e0 = __expf(v0 - mx), e1 = __expf(v1 - mx);
    nw[tid] = e0; nw[tid+256] = e1;
    red[tid] = e0 + e1; __syncthreads();
    for (int s = 128; s > 0; s >>= 1) { if (tid < s) red[tid] += red[tid+s]; __syncthreads(); }
    float inv = 1.f / red[0];
    float acc = 0.f;
    for (int n = 0; n < NA; ++n) acc += nw[n] * xb[(size_t)n*HID + tid];
    p[tid] = acc * inv;
    __syncthreads();
    float s1 = fc1b[tid];
    const float* w1 = fc1w + (size_t)tid*HID;
    for (int k2 = 0; k2 < HID; ++k2) s1 += p[k2] * w1[k2];
    a1[tid] = fmaxf(s1, 0.f);
    __syncthreads();
    if (tid < 2) {
        float s2 = fc2b[tid];
        const float* w2 = fc2w + (size_t)tid*HID;
        for (int k2 = 0; k2 < HID; ++k2) s2 += a1[k2] * w2[k2];
        out[b*2 + tid] = s2;
    }
}

// ---------------- launch ----------------------------------------------------
extern "C" void kernel_launch(void* const* d_in, const int* in_sizes, int n_in,
                              void* d_out, int out_size, void* d_ws, size_t ws_size,
                              hipStream_t stream)
{
    const float* trg  = (const float*)d_in[0];
    const float* src  = (const float*)d_in[1];
    const float* ft_w = (const float*)d_in[2];
    const float* ft_b = (const float*)d_in[3];
    const float* ln_g = (const float*)d_in[4];
    const float* ln_b = (const float*)d_in[5];
    const float* sa_wq = (const float*)d_in[6];  const float* sa_bq = (const float*)d_in[7];
    const float* sa_wk = (const float*)d_in[8];  const float* sa_bk = (const float*)d_in[9];
    const float* sa_wv = (const float*)d_in[10]; const float* sa_bv = (const float*)d_in[11];
    const float* sa_wf = (const float*)d_in[12]; const float* sa_bf = (const float*)d_in[13];
    const float* ea_wq = (const float*)d_in[14]; const float* ea_bq = (const float*)d_in[15];
    const float* ea_wk = (const float*)d_in[16]; const float* ea_bk = (const float*)d_in[17];
    const float* ea_wv = (const float*)d_in[18]; const float* ea_bv = (const float*)d_in[19];
    const float* ea_wf = (const float*)d_in[20]; const float* ea_bf = (const float*)d_in[21];
    const float* pf_w1 = (const float*)d_in[22]; const float* pf_b1 = (const float*)d_in[23];
    const float* pf_w2 = (const float*)d_in[24]; const float* pf_b2 = (const float*)d_in[25];
    const float* fc1w  = (const float*)d_in[26]; const float* fc1b  = (const float*)d_in[27];
    const float* fc2w  = (const float*)d_in[28]; const float* fc2b  = (const float*)d_in[29];
    float* out = (float*)d_out;

    float* ws = (float*)d_ws;
    const size_t NTOK = (size_t)B_*NA;    // 16384
    const size_t NSRC = (size_t)B_*NP;    // 32768
    float* x   = ws;
    float* t   = x + NTOK*HID;
    float* q   = t + NTOK*HID;
    float* k   = q + NTOK*HID;
    float* v   = k + NSRC*HID;
    float* hpf = k;                       // [NTOK, PF] aliases k+v exactly

    int M = (int)NTOK;
    dim3 blk(256);

    ft_kernel<<<M/32, blk, 0, stream>>>(trg, ft_w, ft_b, x);

    for (int l = 0; l < 2; ++l) {
        const size_t wo = (size_t)l*HID*HID, bo = (size_t)l*HID;
        // ---- self attention ----
        gemm_nt<<<dim3(HID/64, M/64), blk, 0, stream>>>(x, sa_wq+wo, sa_bq+bo, q, M, HID, HID, 0);
        gemm_nt<<<dim3(HID/64, M/64), blk, 0, stream>>>(x, sa_wk+wo, sa_bk+bo, k, M, HID, HID, 0);
        gemm_nt<<<dim3(HID/64, M/64), blk, 0, stream>>>(x, sa_wv+wo, sa_bv+bo, v, M, HID, HID, 0);
        attn_kernel<<<dim3(NA/64, NH, B_), blk, 0, stream>>>(q, k, v, t, NA, NA);
        gemm_nt<<<dim3(HID/64, M/64), blk, 0, stream>>>(t, sa_wf+wo, sa_bf+bo, q, M, HID, HID, 0);
        add_ln<<<M, blk, 0, stream>>>(x, q, ln_g+bo, ln_b+bo);
        // ---- cross attention ----
        gemm_nt<<<dim3(HID/64, M/64), blk, 0, stream>>>(x, ea_wq+wo, ea_bq+bo, q, M, HID, HID, 0);
        gemm_nt<<<dim3(HID/64, (int)NSRC/64), blk, 0, stream>>>(src, ea_wk+wo, ea_bk+bo, k, (int)NSRC, HID, HID, 0);
        gemm_nt<<<dim3(HID/64, (int)NSRC/64), blk, 0, stream>>>(src, ea_wv+wo, ea_bv+bo, v, (int)NSRC, HID, HID, 0);
        attn_kernel<<<dim3(NA/64, NH, B_), blk, 0, stream>>>(q, k, v, t, NA, NP);
        gemm_nt<<<dim3(HID/64, M/64), blk, 0, stream>>>(t, ea_wf+wo, ea_bf+bo, q, M, HID, HID, 0);
        add_ln<<<M, blk, 0, stream>>>(x, q, ln_g+bo, ln_b+bo);
        // ---- feed-forward ----
        gemm_nt<<<dim3(PF/64, M/64), blk, 0, stream>>>(x, pf_w1+(size_t)l*PF*HID, pf_b1+(size_t)l*PF, hpf, M, PF, HID, 1);
        gemm_nt<<<dim3(HID/64, M/64), blk, 0, stream>>>(hpf, pf_w2+(size_t)l*HID*PF, pf_b2+bo, t, M, HID, PF, 0);
        add_ln<<<M, blk, 0, stream>>>(x, t, ln_g+bo, ln_b+bo);
    }

    pool_head<<<B_, blk, 0, stream>>>(x, fc1w, fc1b, fc2w, fc2b, out);
}

// Round 2
// 1771.492 us; speedup vs baseline: 1.8473x; 1.8473x over previous
//
#include <hip/hip_runtime.h>
#include <hip/hip_bf16.h>
#include <math.h>

#define B_   32
#define NA   512
#define NP   1024
#define HID  256
#define NH   8
#define DH   32
#define PF   1024

typedef short bf16x8 __attribute__((ext_vector_type(8)));
typedef float f32x4  __attribute__((ext_vector_type(4)));

static __device__ inline unsigned short f2bf(float f) {
    unsigned x = __float_as_uint(f);
    unsigned r = (x + 0x7FFFu + ((x >> 16) & 1u)) >> 16;   // RNE
    return (unsigned short)r;
}

// ---------------- feature transform: x = trg @ ft_w.T + ft_b ----------------
__global__ __launch_bounds__(256) void ft_kernel(const float* __restrict__ trg,
    const float* __restrict__ w, const float* __restrict__ b,
    float* __restrict__ out)
{
    __shared__ float Ws[256][35];
    int tid = threadIdx.x;
    for (int k = 0; k < 34; ++k) Ws[tid][k] = w[tid*34 + k];
    float bias = b[tid];
    __syncthreads();
    int m0 = blockIdx.x * 32;
    for (int r = 0; r < 32; ++r) {
        int m = m0 + r;
        const float* tr = trg + (size_t)m*34;
        float acc = bias;
        #pragma unroll
        for (int k = 0; k < 34; ++k) acc += tr[k] * Ws[tid][k];
        out[(size_t)m*HID + tid] = acc;
    }
}

// ---------------- GEMM: C[M,N] = A[M,K] @ W[N,K]^T + bias ------------------
// mode 0: fp32 out (+optional relu). mode 1: bf16 out. mode 2: bf16 out
// transposed per-head: VT[(b*8+h)*32+d][k], L = sequence length.
__global__ __launch_bounds__(256) void gemm_nt(const float* __restrict__ A,
    const float* __restrict__ W, const float* __restrict__ bias,
    float* __restrict__ C, int M, int N, int K, int relu, int mode, int L)
{
    __shared__ float As[16][68];
    __shared__ float Ws[16][68];
    int t  = threadIdx.x;
    int tx = t & 15, ty = t >> 4;
    int row0 = blockIdx.y * 64, col0 = blockIdx.x * 64;
    int lr = t >> 2, lc = (t & 3) * 4;
    const float* Ap = A + (size_t)(row0 + lr)*K + lc;
    const float* Wp = W + (size_t)(col0 + lr)*K + lc;
    float c[4][4] = {};
    for (int kt = 0; kt < K; kt += 16) {
        float4 av = *(const float4*)(Ap + kt);
        float4 wv = *(const float4*)(Wp + kt);
        __syncthreads();
        As[lc+0][lr] = av.x; As[lc+1][lr] = av.y; As[lc+2][lr] = av.z; As[lc+3][lr] = av.w;
        Ws[lc+0][lr] = wv.x; Ws[lc+1][lr] = wv.y; Ws[lc+2][lr] = wv.z; Ws[lc+3][lr] = wv.w;
        __syncthreads();
        #pragma unroll
        for (int kk = 0; kk < 16; ++kk) {
            float4 a = *(const float4*)&As[kk][ty*4];
            float4 w = *(const float4*)&Ws[kk][tx*4];
            c[0][0] += a.x*w.x; c[0][1] += a.x*w.y; c[0][2] += a.x*w.z; c[0][3] += a.x*w.w;
            c[1][0] += a.y*w.x; c[1][1] += a.y*w.y; c[1][2] += a.y*w.z; c[1][3] += a.y*w.w;
            c[2][0] += a.z*w.x; c[2][1] += a.z*w.y; c[2][2] += a.z*w.z; c[2][3] += a.z*w.w;
            c[3][0] += a.w*w.x; c[3][1] += a.w*w.y; c[3][2] += a.w*w.z; c[3][3] += a.w*w.w;
        }
    }
    float4 bv = *(const float4*)(bias + col0 + tx*4);
    float bb[4] = {bv.x, bv.y, bv.z, bv.w};
    if (mode == 0) {
        #pragma unroll
        for (int i = 0; i < 4; ++i) {
            float* cp = C + (size_t)(row0 + ty*4 + i)*N + col0 + tx*4;
            float4 o;
            o.x = c[i][0] + bb[0]; o.y = c[i][1] + bb[1];
            o.z = c[i][2] + bb[2]; o.w = c[i][3] + bb[3];
            if (relu) { o.x = fmaxf(o.x,0.f); o.y = fmaxf(o.y,0.f);
                        o.z = fmaxf(o.z,0.f); o.w = fmaxf(o.w,0.f); }
            *(float4*)cp = o;
        }
    } else if (mode == 1) {
        unsigned short* Cb = (unsigned short*)C;
        #pragma unroll
        for (int i = 0; i < 4; ++i) {
            ushort4 pk;
            pk.x = f2bf(c[i][0] + bb[0]); pk.y = f2bf(c[i][1] + bb[1]);
            pk.z = f2bf(c[i][2] + bb[2]); pk.w = f2bf(c[i][3] + bb[3]);
            *(ushort4*)(Cb + (size_t)(row0 + ty*4 + i)*N + col0 + tx*4) = pk;
        }
    } else {
        // transposed per-head bf16: VT[((b*8+h)*32 + d)][k]
        unsigned short* Cb = (unsigned short*)C;
        int cc = col0 + tx*4;            // column base (4 cols within one head)
        int hh = cc >> 5, d0 = cc & 31;
        int m0 = row0 + ty*4;
        int bI = m0 / L, kk = m0 % L;
        #pragma unroll
        for (int j = 0; j < 4; ++j) {
            ushort4 pk;
            pk.x = f2bf(c[0][j] + bb[j]); pk.y = f2bf(c[1][j] + bb[j]);
            pk.z = f2bf(c[2][j] + bb[j]); pk.w = f2bf(c[3][j] + bb[j]);
            *(ushort4*)(Cb + (size_t)((bI*NH + hh)*DH + d0 + j)*L + kk) = pk;
        }
    }
}

// ---------------- fused MFMA attention (bf16 inputs, fp32 accum) ------------
// grid: (NA/64, NH, B). Block = 256 thr (4 waves), wave w owns q rows w*16..+15.
__global__ __launch_bounds__(256) void attn_mfma(const unsigned short* __restrict__ Qb,
    const unsigned short* __restrict__ Kb, const unsigned short* __restrict__ VTb,
    float* __restrict__ O, int Lk)
{
    __shared__ __attribute__((aligned(16))) unsigned short Kl[64][40]; // 80B rows
    __shared__ __attribute__((aligned(16))) unsigned short Vl[32][72]; // 144B rows (d-major)
    __shared__ __attribute__((aligned(16))) unsigned short Pl[4][16][40];
    const int b = blockIdx.z, h = blockIdx.y, qt = blockIdx.x;
    const int tid = threadIdx.x, wave = tid >> 6, lane = tid & 63;
    const int lq = lane & 15, g = lane >> 4;

    // hoisted Q fragment: B-operand of mfma(K,Q): lane -> (q=lq, d=8g..8g+7)
    const unsigned short* qp = Qb + ((size_t)(b*NA + qt*64 + wave*16 + lq))*HID + h*DH + g*8;
    bf16x8 qf = *(const bf16x8*)qp;

    f32x4 o0 = {0.f,0.f,0.f,0.f}, o1 = {0.f,0.f,0.f,0.f};
    float m = -1e30f, l = 0.f;
    const float sc = 0.17677669529663687f;   // 1/sqrt(32)

    const unsigned short* Kg = Kb  + ((size_t)b*Lk)*HID + h*DH;
    const unsigned short* Vg = VTb + ((size_t)(b*NH + h))*DH*Lk;

    const int krow = tid >> 2, kseg = tid & 3;
    const int vrow = tid >> 3, vseg = tid & 7;

    for (int kt0 = 0; kt0 < Lk; kt0 += 64) {
        __syncthreads();
        *(bf16x8*)&Kl[krow][kseg*8] = *(const bf16x8*)(Kg + (size_t)(kt0 + krow)*HID + kseg*8);
        *(bf16x8*)&Vl[vrow][vseg*8] = *(const bf16x8*)(Vg + (size_t)vrow*Lk + kt0 + vseg*8);
        __syncthreads();

        // S^T tiles: st[j] holds S[k=j*16+4g+r][q=lq]
        f32x4 st[4];
        #pragma unroll
        for (int j = 0; j < 4; ++j) {
            bf16x8 kf = *(const bf16x8*)&Kl[j*16 + lq][g*8];
            f32x4 z = {0.f,0.f,0.f,0.f};
            st[j] = __builtin_amdgcn_mfma_f32_16x16x32_bf16(kf, qf, z, 0, 0, 0);
        }
        float tm = -1e30f;
        #pragma unroll
        for (int j = 0; j < 4; ++j) {
            #pragma unroll
            for (int r = 0; r < 4; ++r) { st[j][r] *= sc; tm = fmaxf(tm, st[j][r]); }
        }
        tm = fmaxf(tm, __shfl_xor(tm, 16));
        tm = fmaxf(tm, __shfl_xor(tm, 32));
        float mn = fmaxf(m, tm);
        float corr = __expf(m - mn);
        m = mn;
        float rs = 0.f;
        #pragma unroll
        for (int j = 0; j < 4; ++j) {
            float p0 = __expf(st[j][0] - mn), p1 = __expf(st[j][1] - mn);
            float p2 = __expf(st[j][2] - mn), p3 = __expf(st[j][3] - mn);
            rs += p0 + p1 + p2 + p3;
            ushort4 pk;
            pk.x = f2bf(p0); pk.y = f2bf(p1); pk.z = f2bf(p2); pk.w = f2bf(p3);
            *(ushort4*)&Pl[wave][lq][j*16 + g*4] = pk;   // P[q=lq][k=j*16+4g+r]
        }
        rs += __shfl_xor(rs, 16);
        rs += __shfl_xor(rs, 32);
        l = l * corr + rs;
        // broadcast rescale factors for this lane's O rows (4g+r)
        float c0 = __shfl(corr, 4*g + 0), c1 = __shfl(corr, 4*g + 1);
        float c2 = __shfl(corr, 4*g + 2), c3 = __shfl(corr, 4*g + 3);
        o0[0] *= c0; o0[1] *= c1; o0[2] *= c2; o0[3] *= c3;
        o1[0] *= c0; o1[1] *= c1; o1[2] *= c2; o1[3] *= c3;
        // PV: O[q][d] += P[q][k] * V[k][d]
        #pragma unroll
        for (int c = 0; c < 2; ++c) {
            bf16x8 pf = *(const bf16x8*)&Pl[wave][lq][c*32 + g*8];
            bf16x8 v0 = *(const bf16x8*)&Vl[lq][c*32 + g*8];
            bf16x8 v1 = *(const bf16x8*)&Vl[16 + lq][c*32 + g*8];
            o0 = __builtin_amdgcn_mfma_f32_16x16x32_bf16(pf, v0, o0, 0, 0, 0);
            o1 = __builtin_amdgcn_mfma_f32_16x16x32_bf16(pf, v1, o1, 0, 0, 0);
        }
    }
    float linv = 1.f / l;
    float i0 = __shfl(linv, 4*g + 0), i1 = __shfl(linv, 4*g + 1);
    float i2 = __shfl(linv, 4*g + 2), i3 = __shfl(linv, 4*g + 3);
    float* Op = O + ((size_t)(b*NA + qt*64 + wave*16))*HID + h*DH;
    float iv[4] = {i0, i1, i2, i3};
    #pragma unroll
    for (int r = 0; r < 4; ++r) {
        Op[(size_t)(4*g + r)*HID + lq]      = o0[r] * iv[r];
        Op[(size_t)(4*g + r)*HID + 16 + lq] = o1[r] * iv[r];
    }
}

// ---------------- residual add + LayerNorm (in-place on x) -----------------
__global__ __launch_bounds__(256) void add_ln(float* __restrict__ x,
    const float* __restrict__ t, const float* __restrict__ g,
    const float* __restrict__ bt)
{
    __shared__ float red[256];
    int r = blockIdx.x, tid = threadIdx.x;
    size_t idx = (size_t)r*HID + tid;
    float v = x[idx] + t[idx];
    red[tid] = v; __syncthreads();
    for (int s = 128; s > 0; s >>= 1) { if (tid < s) red[tid] += red[tid+s]; __syncthreads(); }
    float mean = red[0] * (1.f/HID); __syncthreads();
    float d = v - mean;
    red[tid] = d*d; __syncthreads();
    for (int s = 128; s > 0; s >>= 1) { if (tid < s) red[tid] += red[tid+s]; __syncthreads(); }
    float var = red[0] * (1.f/HID);
    float rs = rsqrtf(var + 1e-5f);
    x[idx] = d * rs * g[tid] + bt[tid];
}

// ---------------- pooling + FC head ----------------------------------------
__global__ __launch_bounds__(256) void pool_head(const float* __restrict__ x,
    const float* __restrict__ fc1w, const float* __restrict__ fc1b,
    const float* __restrict__ fc2w, const float* __restrict__ fc2b,
    float* __restrict__ out)
{
    __shared__ float nw[512];
    __shared__ float p[256];
    __shared__ float a1[256];
    __shared__ float red[256];
    int b = blockIdx.x, tid = threadIdx.x;
    int wid = tid >> 6, lane = tid & 63;
    const float* xb = x + (size_t)b*NA*HID;
    for (int n = wid; n < NA; n += 4) {
        float s = 0.f;
        for (int hh = lane; hh < HID; hh += 64) { float vv = xb[(size_t)n*HID + hh]; s += vv*vv; }
        for (int off = 32; off > 0; off >>= 1) s += __shfl_down(s, off, 64);
        if (lane == 0) nw[n] = sqrtf(s);
    }
    __syncthreads();
    float v0 = nw[tid], v1 = nw[tid+256];
    red[tid] = fmaxf(v0, v1); __syncthreads();
    for (int s = 128; s > 0; s >>= 1) { if (tid < s) red[tid] = fmaxf(red[tid], red[tid+s]); __syncthreads(); }
    float mx = red[0]; __syncthreads();
    float e0 = __expf(v0 - mx), e1 = __expf(v1 - mx);
    nw[tid] = e0; nw[tid+256] = e1;
    red[tid] = e0 + e1; __syncthreads();
    for (int s = 128; s > 0; s >>= 1) { if (tid < s) red[tid] += red[tid+s]; __syncthreads(); }
    float inv = 1.f / red[0];
    float acc = 0.f;
    for (int n = 0; n < NA; ++n) acc += nw[n] * xb[(size_t)n*HID + tid];
    p[tid] = acc * inv;
    __syncthreads();
    float s1 = fc1b[tid];
    const float* w1 = fc1w + (size_t)tid*HID;
    for (int k2 = 0; k2 < HID; ++k2) s1 += p[k2] * w1[k2];
    a1[tid] = fmaxf(s1, 0.f);
    __syncthreads();
    if (tid < 2) {
        float s2 = fc2b[tid];
        const float* w2 = fc2w + (size_t)tid*HID;
        for (int k2 = 0; k2 < HID; ++k2) s2 += a1[k2] * w2[k2];
        out[b*2 + tid] = s2;
    }
}

// ---------------- launch ----------------------------------------------------
extern "C" void kernel_launch(void* const* d_in, const int* in_sizes, int n_in,
                              void* d_out, int out_size, void* d_ws, size_t ws_size,
                              hipStream_t stream)
{
    const float* trg  = (const float*)d_in[0];
    const float* src  = (const float*)d_in[1];
    const float* ft_w = (const float*)d_in[2];
    const float* ft_b = (const float*)d_in[3];
    const float* ln_g = (const float*)d_in[4];
    const float* ln_b = (const float*)d_in[5];
    const float* sa_wq = (const float*)d_in[6];  const float* sa_bq = (const float*)d_in[7];
    const float* sa_wk = (const float*)d_in[8];  const float* sa_bk = (const float*)d_in[9];
    const float* sa_wv = (const float*)d_in[10]; const float* sa_bv = (const float*)d_in[11];
    const float* sa_wf = (const float*)d_in[12]; const float* sa_bf = (const float*)d_in[13];
    const float* ea_wq = (const float*)d_in[14]; const float* ea_bq = (const float*)d_in[15];
    const float* ea_wk = (const float*)d_in[16]; const float* ea_bk = (const float*)d_in[17];
    const float* ea_wv = (const float*)d_in[18]; const float* ea_bv = (const float*)d_in[19];
    const float* ea_wf = (const float*)d_in[20]; const float* ea_bf = (const float*)d_in[21];
    const float* pf_w1 = (const float*)d_in[22]; const float* pf_b1 = (const float*)d_in[23];
    const float* pf_w2 = (const float*)d_in[24]; const float* pf_b2 = (const float*)d_in[25];
    const float* fc1w  = (const float*)d_in[26]; const float* fc1b  = (const float*)d_in[27];
    const float* fc2w  = (const float*)d_in[28]; const float* fc2b  = (const float*)d_in[29];
    float* out = (float*)d_out;

    const size_t NTOK = (size_t)B_*NA;    // 16384
    const size_t NSRC = (size_t)B_*NP;    // 32768
    float* ws = (float*)d_ws;
    float* x   = ws;                       // [NTOK,HID] fp32
    float* t   = x + NTOK*HID;             // [NTOK,HID] fp32 (attn out / ffn out)
    float* u   = t + NTOK*HID;             // [NTOK,HID] fp32 (f-proj out)
    float* rgn = u + NTOK*HID;             // 64 MB region: bf16 qkv OR ffn hidden
    unsigned short* qb  = (unsigned short*)rgn;          // [NTOK,HID] bf16  (8 MB)
    unsigned short* kb  = qb + NSRC*HID/2*0 + NTOK*HID;  // [NSRC,HID] bf16 (16 MB)
    unsigned short* vTb = kb + NSRC*HID;                 // [NSRC,HID] bf16 (16 MB)
    float* hpf = rgn;                      // [NTOK,PF] fp32 aliases qb..vTb+24MB

    int M = (int)NTOK;
    dim3 blk(256);

    ft_kernel<<<M/32, blk, 0, stream>>>(trg, ft_w, ft_b, x);

    for (int l = 0; l < 2; ++l) {
        const size_t wo = (size_t)l*HID*HID, bo = (size_t)l*HID;
        // ---- self attention ----
        gemm_nt<<<dim3(HID/64, M/64), blk, 0, stream>>>(x, sa_wq+wo, sa_bq+bo, (float*)qb,  M, HID, HID, 0, 1, NA);
        gemm_nt<<<dim3(HID/64, M/64), blk, 0, stream>>>(x, sa_wk+wo, sa_bk+bo, (float*)kb,  M, HID, HID, 0, 1, NA);
        gemm_nt<<<dim3(HID/64, M/64), blk, 0, stream>>>(x, sa_wv+wo, sa_bv+bo, (float*)vTb, M, HID, HID, 0, 2, NA);
        attn_mfma<<<dim3(NA/64, NH, B_), blk, 0, stream>>>(qb, kb, vTb, t, NA);
        gemm_nt<<<dim3(HID/64, M/64), blk, 0, stream>>>(t, sa_wf+wo, sa_bf+bo, u, M, HID, HID, 0, 0, 0);
        add_ln<<<M, blk, 0, stream>>>(x, u, ln_g+bo, ln_b+bo);
        // ---- cross attention ----
        gemm_nt<<<dim3(HID/64, M/64), blk, 0, stream>>>(x, ea_wq+wo, ea_bq+bo, (float*)qb, M, HID, HID, 0, 1, NA);
        gemm_nt<<<dim3(HID/64, (int)NSRC/64), blk, 0, stream>>>(src, ea_wk+wo, ea_bk+bo, (float*)kb,  (int)NSRC, HID, HID, 0, 1, NP);
        gemm_nt<<<dim3(HID/64, (int)NSRC/64), blk, 0, stream>>>(src, ea_wv+wo, ea_bv+bo, (float*)vTb, (int)NSRC, HID, HID, 0, 2, NP);
        attn_mfma<<<dim3(NA/64, NH, B_), blk, 0, stream>>>(qb, kb, vTb, t, NP);
        gemm_nt<<<dim3(HID/64, M/64), blk, 0, stream>>>(t, ea_wf+wo, ea_bf+bo, u, M, HID, HID, 0, 0, 0);
        add_ln<<<M, blk, 0, stream>>>(x, u, ln_g+bo, ln_b+bo);
        // ---- feed-forward ----
        gemm_nt<<<dim3(PF/64, M/64), blk, 0, stream>>>(x, pf_w1+(size_t)l*PF*HID, pf_b1+(size_t)l*PF, hpf, M, PF, HID, 1, 0, 0);
        gemm_nt<<<dim3(HID/64, M/64), blk, 0, stream>>>(hpf, pf_w2+(size_t)l*HID*PF, pf_b2+bo, t, M, HID, PF, 0, 0, 0);
        add_ln<<<M, blk, 0, stream>>>(x, t, ln_g+bo, ln_b+bo);
    }

    pool_head<<<B_, blk, 0, stream>>>(x, fc1w, fc1b, fc2w, fc2b, out);
}

// Round 3
// 838.742 us; speedup vs baseline: 3.9017x; 2.1121x over previous
//
#include <hip/hip_runtime.h>
#include <hip/hip_bf16.h>
#include <math.h>

#define B_   32
#define NA   512
#define NP   1024
#define HID  256
#define NH   8
#define DH   32
#define PF   1024

typedef short bf16x8 __attribute__((ext_vector_type(8)));
typedef float f32x4  __attribute__((ext_vector_type(4)));

static __device__ inline unsigned short f2bf(float f) {
    __hip_bfloat16 h = __float2bfloat16(f);   // RNE; pairs fuse to v_cvt_pk_bf16_f32
    unsigned short u;
    __builtin_memcpy(&u, &h, 2);
    return u;
}
static __device__ inline bf16x8 pack8(float4 a, float4 b) {
    bf16x8 r;
    r[0] = (short)f2bf(a.x); r[1] = (short)f2bf(a.y);
    r[2] = (short)f2bf(a.z); r[3] = (short)f2bf(a.w);
    r[4] = (short)f2bf(b.x); r[5] = (short)f2bf(b.y);
    r[6] = (short)f2bf(b.z); r[7] = (short)f2bf(b.w);
    return r;
}

// ---------------- feature transform: x = trg @ ft_w.T + ft_b ----------------
__global__ __launch_bounds__(256) void ft_kernel(const float* __restrict__ trg,
    const float* __restrict__ w, const float* __restrict__ b,
    float* __restrict__ out)
{
    __shared__ float Ws[256][35];
    int tid = threadIdx.x;
    for (int k = 0; k < 34; ++k) Ws[tid][k] = w[tid*34 + k];
    float bias = b[tid];
    __syncthreads();
    int m0 = blockIdx.x * 32;
    for (int r = 0; r < 32; ++r) {
        int m = m0 + r;
        const float* tr = trg + (size_t)m*34;
        float acc = bias;
        #pragma unroll
        for (int k = 0; k < 34; ++k) acc += tr[k] * Ws[tid][k];
        out[(size_t)m*HID + tid] = acc;
    }
}

// ---------------- bf16 MFMA GEMM core: C[M,N] = A[M,K] @ W[N,K]^T + bias ----
// AIN: 0 = A fp32 (converted in staging), 1 = A bf16.
// mode: 0 fp32 out; 1 bf16 out; 2 bf16 out per-head transposed
//       VT[((bI*NH+h)*DH+d)*L + k]; 3 bf16 out + relu.
template<int AIN>
static __device__ inline void gemm_core(const void* __restrict__ Av,
    const float* __restrict__ W, const float* __restrict__ bias,
    void* __restrict__ Cv, int M, int N, int K, int mode, int L,
    int bx, int by)
{
    __shared__ __attribute__((aligned(16))) unsigned short As[128][72]; // 144B rows
    __shared__ __attribute__((aligned(16))) unsigned short Bs[64][72];
    const int tid = threadIdx.x;
    const int wave = tid >> 6, lane = tid & 63, lq = lane & 15, g = lane >> 4;
    const int wr = wave >> 1, wc = wave & 1;
    const int m0 = by * 128, n0 = bx * 64;

    const int ar = tid >> 1, ac = (tid & 1) * 32;   // A stage: 2 thr/row, 32 elems
    const int br = tid >> 2, bc = (tid & 3) * 16;   // W stage: 4 thr/row, 16 elems

    const float* Af = (const float*)Av;
    const unsigned short* Ab = (const unsigned short*)Av;

    f32x4 acc[4][2] = {};
    bf16x8 sa[4], sw[2];

    auto LOAD = [&](int kt) {
        const int k0 = kt * 64;
        if constexpr (AIN == 0) {
            const float* Ap = Af + (size_t)(m0 + ar)*K + k0 + ac;
            #pragma unroll
            for (int i = 0; i < 4; ++i)
                sa[i] = pack8(*(const float4*)(Ap + i*8), *(const float4*)(Ap + i*8 + 4));
        } else {
            const unsigned short* Ap = Ab + (size_t)(m0 + ar)*K + k0 + ac;
            #pragma unroll
            for (int i = 0; i < 4; ++i)
                sa[i] = *(const bf16x8*)(Ap + i*8);
        }
        const float* Wp = W + (size_t)(n0 + br)*K + k0 + bc;
        #pragma unroll
        for (int i = 0; i < 2; ++i)
            sw[i] = pack8(*(const float4*)(Wp + i*8), *(const float4*)(Wp + i*8 + 4));
    };
    auto STORE = [&]() {
        #pragma unroll
        for (int i = 0; i < 4; ++i) *(bf16x8*)&As[ar][ac + i*8] = sa[i];
        #pragma unroll
        for (int i = 0; i < 2; ++i) *(bf16x8*)&Bs[br][bc + i*8] = sw[i];
    };

    const int nk = K / 64;
    LOAD(0);
    for (int kt = 0; kt < nk; ++kt) {
        __syncthreads();
        STORE();
        __syncthreads();
        if (kt + 1 < nk) LOAD(kt + 1);
        #pragma unroll
        for (int ks = 0; ks < 2; ++ks) {
            bf16x8 bf0 = *(const bf16x8*)&Bs[wc*32 +  0 + lq][ks*32 + g*8];
            bf16x8 bf1 = *(const bf16x8*)&Bs[wc*32 + 16 + lq][ks*32 + g*8];
            #pragma unroll
            for (int i = 0; i < 4; ++i) {
                bf16x8 af = *(const bf16x8*)&As[wr*64 + i*16 + lq][ks*32 + g*8];
                acc[i][0] = __builtin_amdgcn_mfma_f32_16x16x32_bf16(af, bf0, acc[i][0], 0, 0, 0);
                acc[i][1] = __builtin_amdgcn_mfma_f32_16x16x32_bf16(af, bf1, acc[i][1], 0, 0, 0);
            }
        }
    }

    float bb[2];
    #pragma unroll
    for (int j = 0; j < 2; ++j) bb[j] = bias[n0 + wc*32 + j*16 + lq];

    #pragma unroll
    for (int i = 0; i < 4; ++i) {
        const int mb = m0 + wr*64 + i*16 + 4*g;
        #pragma unroll
        for (int j = 0; j < 2; ++j) {
            const int n = n0 + wc*32 + j*16 + lq;
            f32x4 v = acc[i][j];
            v[0] += bb[j]; v[1] += bb[j]; v[2] += bb[j]; v[3] += bb[j];
            if (mode == 0) {
                float* Cf = (float*)Cv;
                #pragma unroll
                for (int r = 0; r < 4; ++r) Cf[(size_t)(mb + r)*N + n] = v[r];
            } else if (mode == 1) {
                unsigned short* Cb = (unsigned short*)Cv;
                #pragma unroll
                for (int r = 0; r < 4; ++r) Cb[(size_t)(mb + r)*N + n] = f2bf(v[r]);
            } else if (mode == 3) {
                unsigned short* Cb = (unsigned short*)Cv;
                #pragma unroll
                for (int r = 0; r < 4; ++r) Cb[(size_t)(mb + r)*N + n] = f2bf(fmaxf(v[r], 0.f));
            } else {
                unsigned short* Cb = (unsigned short*)Cv;
                const int bI = mb / L, kk = mb % L;
                const int hh = n >> 5, d0 = n & 31;
                ushort4 pk;
                pk.x = f2bf(v[0]); pk.y = f2bf(v[1]); pk.z = f2bf(v[2]); pk.w = f2bf(v[3]);
                *(ushort4*)(Cb + ((size_t)(bI*NH + hh)*DH + d0)*L + kk) = pk;
            }
        }
    }
}

template<int AIN>
__global__ __launch_bounds__(256) void gemm_mfma(const void* __restrict__ A,
    const float* __restrict__ W, const float* __restrict__ bias,
    void* __restrict__ C, int M, int N, int K, int mode, int L)
{
    gemm_core<AIN>(A, W, bias, C, M, N, K, mode, L, blockIdx.x, blockIdx.y);
}

// fused Q/K/V projections: blockIdx.z selects which
__global__ __launch_bounds__(256) void qkv_mfma(const float* __restrict__ Aq,
    const float* __restrict__ Akv,
    const float* __restrict__ Wq, const float* __restrict__ bq,
    const float* __restrict__ Wk, const float* __restrict__ bk,
    const float* __restrict__ Wv, const float* __restrict__ bv,
    void* __restrict__ qo, void* __restrict__ ko, void* __restrict__ vo,
    int Mq, int Mkv, int L)
{
    const int z = blockIdx.z;
    const float* A = (z == 0) ? Aq : Akv;
    const float* W = (z == 0) ? Wq : ((z == 1) ? Wk : Wv);
    const float* bb = (z == 0) ? bq : ((z == 1) ? bk : bv);
    void* C = (z == 0) ? qo : ((z == 1) ? ko : vo);
    const int M = (z == 0) ? Mq : Mkv;
    const int mode = (z == 2) ? 2 : 1;
    if ((int)blockIdx.y * 128 >= M) return;
    gemm_core<0>(A, W, bb, C, M, HID, HID, mode, L, blockIdx.x, blockIdx.y);
}

// ---------------- fused MFMA attention (bf16 inputs, fp32 accum) ------------
__global__ __launch_bounds__(256) void attn_mfma(const unsigned short* __restrict__ Qb,
    const unsigned short* __restrict__ Kb, const unsigned short* __restrict__ VTb,
    float* __restrict__ O, int Lk)
{
    __shared__ __attribute__((aligned(16))) unsigned short Kl[64][40];
    __shared__ __attribute__((aligned(16))) unsigned short Vl[32][72];
    __shared__ __attribute__((aligned(16))) unsigned short Pl[4][16][40];
    const int b = blockIdx.z, h = blockIdx.y, qt = blockIdx.x;
    const int tid = threadIdx.x, wave = tid >> 6, lane = tid & 63;
    const int lq = lane & 15, g = lane >> 4;

    const unsigned short* qp = Qb + ((size_t)(b*NA + qt*64 + wave*16 + lq))*HID + h*DH + g*8;
    bf16x8 qf = *(const bf16x8*)qp;

    f32x4 o0 = {0.f,0.f,0.f,0.f}, o1 = {0.f,0.f,0.f,0.f};
    float m = -1e30f, l = 0.f;
    const float sc = 0.17677669529663687f;   // 1/sqrt(32)

    const unsigned short* Kg = Kb  + ((size_t)b*Lk)*HID + h*DH;
    const unsigned short* Vg = VTb + ((size_t)(b*NH + h))*DH*Lk;

    const int krow = tid >> 2, kseg = tid & 3;
    const int vrow = tid >> 3, vseg = tid & 7;

    for (int kt0 = 0; kt0 < Lk; kt0 += 64) {
        __syncthreads();
        *(bf16x8*)&Kl[krow][kseg*8] = *(const bf16x8*)(Kg + (size_t)(kt0 + krow)*HID + kseg*8);
        *(bf16x8*)&Vl[vrow][vseg*8] = *(const bf16x8*)(Vg + (size_t)vrow*Lk + kt0 + vseg*8);
        __syncthreads();

        f32x4 st[4];
        #pragma unroll
        for (int j = 0; j < 4; ++j) {
            bf16x8 kf = *(const bf16x8*)&Kl[j*16 + lq][g*8];
            f32x4 z = {0.f,0.f,0.f,0.f};
            st[j] = __builtin_amdgcn_mfma_f32_16x16x32_bf16(kf, qf, z, 0, 0, 0);
        }
        float tm = -1e30f;
        #pragma unroll
        for (int j = 0; j < 4; ++j) {
            #pragma unroll
            for (int r = 0; r < 4; ++r) { st[j][r] *= sc; tm = fmaxf(tm, st[j][r]); }
        }
        tm = fmaxf(tm, __shfl_xor(tm, 16));
        tm = fmaxf(tm, __shfl_xor(tm, 32));
        float mn = fmaxf(m, tm);
        float corr = __expf(m - mn);
        m = mn;
        float rs = 0.f;
        #pragma unroll
        for (int j = 0; j < 4; ++j) {
            float p0 = __expf(st[j][0] - mn), p1 = __expf(st[j][1] - mn);
            float p2 = __expf(st[j][2] - mn), p3 = __expf(st[j][3] - mn);
            rs += p0 + p1 + p2 + p3;
            ushort4 pk;
            pk.x = f2bf(p0); pk.y = f2bf(p1); pk.z = f2bf(p2); pk.w = f2bf(p3);
            *(ushort4*)&Pl[wave][lq][j*16 + g*4] = pk;
        }
        rs += __shfl_xor(rs, 16);
        rs += __shfl_xor(rs, 32);
        l = l * corr + rs;
        float c0 = __shfl(corr, 4*g + 0), c1 = __shfl(corr, 4*g + 1);
        float c2 = __shfl(corr, 4*g + 2), c3 = __shfl(corr, 4*g + 3);
        o0[0] *= c0; o0[1] *= c1; o0[2] *= c2; o0[3] *= c3;
        o1[0] *= c0; o1[1] *= c1; o1[2] *= c2; o1[3] *= c3;
        #pragma unroll
        for (int c = 0; c < 2; ++c) {
            bf16x8 pf = *(const bf16x8*)&Pl[wave][lq][c*32 + g*8];
            bf16x8 v0 = *(const bf16x8*)&Vl[lq][c*32 + g*8];
            bf16x8 v1 = *(const bf16x8*)&Vl[16 + lq][c*32 + g*8];
            o0 = __builtin_amdgcn_mfma_f32_16x16x32_bf16(pf, v0, o0, 0, 0, 0);
            o1 = __builtin_amdgcn_mfma_f32_16x16x32_bf16(pf, v1, o1, 0, 0, 0);
        }
    }
    float linv = 1.f / l;
    float i0 = __shfl(linv, 4*g + 0), i1 = __shfl(linv, 4*g + 1);
    float i2 = __shfl(linv, 4*g + 2), i3 = __shfl(linv, 4*g + 3);
    float* Op = O + ((size_t)(b*NA + qt*64 + wave*16))*HID + h*DH;
    float iv[4] = {i0, i1, i2, i3};
    #pragma unroll
    for (int r = 0; r < 4; ++r) {
        Op[(size_t)(4*g + r)*HID + lq]      = o0[r] * iv[r];
        Op[(size_t)(4*g + r)*HID + 16 + lq] = o1[r] * iv[r];
    }
}

// ---------------- residual add + LayerNorm (wave per row, in-place) ---------
__global__ __launch_bounds__(256) void add_ln(float* __restrict__ x,
    const float* __restrict__ t, const float* __restrict__ g,
    const float* __restrict__ bt)
{
    const int row = blockIdx.x*4 + (threadIdx.x >> 6);
    const int lane = threadIdx.x & 63;
    const size_t base = (size_t)row*HID + lane*4;
    float4 v = *(const float4*)(x + base);
    float4 tv = *(const float4*)(t + base);
    v.x += tv.x; v.y += tv.y; v.z += tv.z; v.w += tv.w;
    float s = v.x + v.y + v.z + v.w;
    #pragma unroll
    for (int o = 32; o > 0; o >>= 1) s += __shfl_xor(s, o);
    float mean = s * (1.f/256.f);
    float4 d = {v.x - mean, v.y - mean, v.z - mean, v.w - mean};
    float q2 = d.x*d.x + d.y*d.y + d.z*d.z + d.w*d.w;
    #pragma unroll
    for (int o = 32; o > 0; o >>= 1) q2 += __shfl_xor(q2, o);
    float rs = rsqrtf(q2*(1.f/256.f) + 1e-5f);
    float4 gv = *(const float4*)(g + lane*4);
    float4 bv = *(const float4*)(bt + lane*4);
    float4 ov;
    ov.x = d.x*rs*gv.x + bv.x; ov.y = d.y*rs*gv.y + bv.y;
    ov.z = d.z*rs*gv.z + bv.z; ov.w = d.w*rs*gv.w + bv.w;
    *(float4*)(x + base) = ov;
}

// ---------------- pooling + FC head ----------------------------------------
__global__ __launch_bounds__(256) void pool_head(const float* __restrict__ x,
    const float* __restrict__ fc1w, const float* __restrict__ fc1b,
    const float* __restrict__ fc2w, const float* __restrict__ fc2b,
    float* __restrict__ out)
{
    __shared__ float nw[NA];
    __shared__ float part[4][HID];
    __shared__ float p[HID];
    __shared__ float a1[HID];
    __shared__ float red[256];
    const int b = blockIdx.x, tid = threadIdx.x;
    const int wave = tid >> 6, lane = tid & 63;
    const float* xb = x + (size_t)b*NA*HID;

    // pass 1: row norms (wave per row, float4 per lane)
    for (int n = wave; n < NA; n += 4) {
        float4 v = *(const float4*)(xb + (size_t)n*HID + lane*4);
        float s = v.x*v.x + v.y*v.y + v.z*v.z + v.w*v.w;
        #pragma unroll
        for (int o = 32; o > 0; o >>= 1) s += __shfl_xor(s, o);
        if (lane == 0) nw[n] = sqrtf(s);
    }
    __syncthreads();
    // softmax over 512 norms
    float v0 = nw[tid], v1 = nw[tid + 256];
    red[tid] = fmaxf(v0, v1); __syncthreads();
    for (int s = 128; s > 0; s >>= 1) { if (tid < s) red[tid] = fmaxf(red[tid], red[tid+s]); __syncthreads(); }
    float mx = red[0]; __syncthreads();
    float e0 = __expf(v0 - mx), e1 = __expf(v1 - mx);
    nw[tid] = e0; nw[tid + 256] = e1;
    red[tid] = e0 + e1; __syncthreads();
    for (int s = 128; s > 0; s >>= 1) { if (tid < s) red[tid] += red[tid+s]; __syncthreads(); }
    float inv = 1.f / red[0];
    __syncthreads();
    // pass 2: weighted sum
    float4 acc = {0.f,0.f,0.f,0.f};
    for (int n = wave; n < NA; n += 4) {
        float wgt = nw[n];
        float4 v = *(const float4*)(xb + (size_t)n*HID + lane*4);
        acc.x += wgt*v.x; acc.y += wgt*v.y; acc.z += wgt*v.z; acc.w += wgt*v.w;
    }
    *(float4*)&part[wave][lane*4] = acc;
    __syncthreads();
    p[tid] = (part[0][tid] + part[1][tid] + part[2][tid] + part[3][tid]) * inv;
    __syncthreads();
    // fc1 (vectorized k-loop)
    float s1 = fc1b[tid];
    const float* w1 = fc1w + (size_t)tid*HID;
    for (int k2 = 0; k2 < HID; k2 += 4) {
        float4 w = *(const float4*)(w1 + k2);
        s1 += p[k2]*w.x + p[k2+1]*w.y + p[k2+2]*w.z + p[k2+3]*w.w;
    }
    a1[tid] = fmaxf(s1, 0.f);
    __syncthreads();
    if (tid < 2) {
        float s2 = fc2b[tid];
        const float* w2 = fc2w + (size_t)tid*HID;
        for (int k2 = 0; k2 < HID; ++k2) s2 += a1[k2] * w2[k2];
        out[b*2 + tid] = s2;
    }
}

// ---------------- launch ----------------------------------------------------
extern "C" void kernel_launch(void* const* d_in, const int* in_sizes, int n_in,
                              void* d_out, int out_size, void* d_ws, size_t ws_size,
                              hipStream_t stream)
{
    const float* trg  = (const float*)d_in[0];
    const float* src  = (const float*)d_in[1];
    const float* ft_w = (const float*)d_in[2];
    const float* ft_b = (const float*)d_in[3];
    const float* ln_g = (const float*)d_in[4];
    const float* ln_b = (const float*)d_in[5];
    const float* sa_wq = (const float*)d_in[6];  const float* sa_bq = (const float*)d_in[7];
    const float* sa_wk = (const float*)d_in[8];  const float* sa_bk = (const float*)d_in[9];
    const float* sa_wv = (const float*)d_in[10]; const float* sa_bv = (const float*)d_in[11];
    const float* sa_wf = (const float*)d_in[12]; const float* sa_bf = (const float*)d_in[13];
    const float* ea_wq = (const float*)d_in[14]; const float* ea_bq = (const float*)d_in[15];
    const float* ea_wk = (const float*)d_in[16]; const float* ea_bk = (const float*)d_in[17];
    const float* ea_wv = (const float*)d_in[18]; const float* ea_bv = (const float*)d_in[19];
    const float* ea_wf = (const float*)d_in[20]; const float* ea_bf = (const float*)d_in[21];
    const float* pf_w1 = (const float*)d_in[22]; const float* pf_b1 = (const float*)d_in[23];
    const float* pf_w2 = (const float*)d_in[24]; const float* pf_b2 = (const float*)d_in[25];
    const float* fc1w  = (const float*)d_in[26]; const float* fc1b  = (const float*)d_in[27];
    const float* fc2w  = (const float*)d_in[28]; const float* fc2b  = (const float*)d_in[29];
    float* out = (float*)d_out;

    const size_t NTOK = (size_t)B_*NA;    // 16384
    const size_t NSRC = (size_t)B_*NP;    // 32768
    float* ws = (float*)d_ws;
    float* x = ws;                         // [NTOK,HID] fp32 master
    float* t = x + NTOK*HID;               // [NTOK,HID] fp32 (attn out / ffn2 out)
    float* u = t + NTOK*HID;               // [NTOK,HID] fp32 (f-proj out)
    unsigned short* qb  = (unsigned short*)(u + NTOK*HID);  // [NTOK,HID] bf16
    unsigned short* kb  = qb + NTOK*HID;                    // [NSRC,HID] bf16
    unsigned short* vTb = kb + NSRC*HID;                    // [NSRC,HID] bf16 (transposed)
    unsigned short* hb  = qb;              // [NTOK,PF] bf16, aliases qb/kb/vTb

    const int M = (int)NTOK;
    dim3 blk(256);

    ft_kernel<<<M/32, blk, 0, stream>>>(trg, ft_w, ft_b, x);

    for (int l = 0; l < 2; ++l) {
        const size_t wo = (size_t)l*HID*HID, bo = (size_t)l*HID;
        // ---- self attention ----
        qkv_mfma<<<dim3(HID/64, M/128, 3), blk, 0, stream>>>(x, x,
            sa_wq+wo, sa_bq+bo, sa_wk+wo, sa_bk+bo, sa_wv+wo, sa_bv+bo,
            qb, kb, vTb, M, M, NA);
        attn_mfma<<<dim3(NA/64, NH, B_), blk, 0, stream>>>(qb, kb, vTb, t, NA);
        gemm_mfma<0><<<dim3(HID/64, M/128), blk, 0, stream>>>(t, sa_wf+wo, sa_bf+bo, u, M, HID, HID, 0, 0);
        add_ln<<<M/4, blk, 0, stream>>>(x, u, ln_g+bo, ln_b+bo);
        // ---- cross attention ----
        qkv_mfma<<<dim3(HID/64, (int)NSRC/128, 3), blk, 0, stream>>>(x, src,
            ea_wq+wo, ea_bq+bo, ea_wk+wo, ea_bk+bo, ea_wv+wo, ea_bv+bo,
            qb, kb, vTb, M, (int)NSRC, NP);
        attn_mfma<<<dim3(NA/64, NH, B_), blk, 0, stream>>>(qb, kb, vTb, t, NP);
        gemm_mfma<0><<<dim3(HID/64, M/128), blk, 0, stream>>>(t, ea_wf+wo, ea_bf+bo, u, M, HID, HID, 0, 0);
        add_ln<<<M/4, blk, 0, stream>>>(x, u, ln_g+bo, ln_b+bo);
        // ---- feed-forward ----
        gemm_mfma<0><<<dim3(PF/64, M/128), blk, 0, stream>>>(x, pf_w1+(size_t)l*PF*HID, pf_b1+(size_t)l*PF, hb, M, PF, HID, 3, 0);
        gemm_mfma<1><<<dim3(HID/64, M/128), blk, 0, stream>>>(hb, pf_w2+(size_t)l*HID*PF, pf_b2+bo, t, M, HID, PF, 0, 0);
        add_ln<<<M/4, blk, 0, stream>>>(x, t, ln_g+bo, ln_b+bo);
    }

    pool_head<<<B_, blk, 0, stream>>>(x, fc1w, fc1b, fc2w, fc2b, out);
}

// Round 4
// 599.948 us; speedup vs baseline: 5.4547x; 1.3980x over previous
//
#include <hip/hip_runtime.h>
#include <hip/hip_bf16.h>
#include <math.h>

#define B_   32
#define NA   512
#define NP   1024
#define HID  256
#define NH   8
#define DH   32
#define PF   1024

typedef short bf16x8 __attribute__((ext_vector_type(8)));
typedef float f32x4  __attribute__((ext_vector_type(4)));

static __device__ inline unsigned short f2bf(float f) {
    __hip_bfloat16 h = __float2bfloat16(f);   // RNE; pairs fuse to v_cvt_pk_bf16_f32
    unsigned short u;
    __builtin_memcpy(&u, &h, 2);
    return u;
}
static __device__ inline bf16x8 pack8(float4 a, float4 b) {
    bf16x8 r;
    r[0] = (short)f2bf(a.x); r[1] = (short)f2bf(a.y);
    r[2] = (short)f2bf(a.z); r[3] = (short)f2bf(a.w);
    r[4] = (short)f2bf(b.x); r[5] = (short)f2bf(b.y);
    r[6] = (short)f2bf(b.z); r[7] = (short)f2bf(b.w);
    return r;
}

// ---------------- feature transform: x = trg @ ft_w.T + ft_b (fp32 + bf16) --
__global__ __launch_bounds__(256) void ft_kernel(const float* __restrict__ trg,
    const float* __restrict__ w, const float* __restrict__ b,
    float* __restrict__ out, unsigned short* __restrict__ outb)
{
    __shared__ float Ws[256][35];
    int tid = threadIdx.x;
    for (int k = 0; k < 34; ++k) Ws[tid][k] = w[tid*34 + k];
    float bias = b[tid];
    __syncthreads();
    int m0 = blockIdx.x * 32;
    for (int r = 0; r < 32; ++r) {
        int m = m0 + r;
        const float* tr = trg + (size_t)m*34;
        float acc = bias;
        #pragma unroll
        for (int k = 0; k < 34; ++k) acc += tr[k] * Ws[tid][k];
        out [(size_t)m*HID + tid] = acc;
        outb[(size_t)m*HID + tid] = f2bf(acc);
    }
}

// ---------------- fp32 -> bf16 bulk convert ---------------------------------
__global__ __launch_bounds__(256) void cvt_bf16(const float* __restrict__ in,
    unsigned short* __restrict__ outb, int n8)
{
    int i = blockIdx.x*256 + threadIdx.x;
    int stride = gridDim.x*256;
    for (; i < n8; i += stride) {
        float4 a = *(const float4*)(in + (size_t)i*8);
        float4 b = *(const float4*)(in + (size_t)i*8 + 4);
        *(bf16x8*)(outb + (size_t)i*8) = pack8(a, b);
    }
}

// ---------------- bf16 MFMA GEMM core: C[M,N] = A[M,K] @ W[N,K]^T + bias ----
// A is bf16. mode: 0 fp32 out; 1 bf16 out; 2 bf16 out per-head transposed
//       VT[((bI*NH+h)*DH+d)*L + k]; 3 bf16 out + relu.
static __device__ inline void gemm_core(const unsigned short* __restrict__ Ab,
    const float* __restrict__ W, const float* __restrict__ bias,
    void* __restrict__ Cv, int M, int N, int K, int mode, int L,
    int bx, int by)
{
    __shared__ __attribute__((aligned(16))) unsigned short As[128][72]; // 144B rows
    __shared__ __attribute__((aligned(16))) unsigned short Bs[64][72];
    const int tid = threadIdx.x;
    const int wave = tid >> 6, lane = tid & 63, lq = lane & 15, g = lane >> 4;
    const int wr = wave >> 1, wc = wave & 1;
    const int m0 = by * 128, n0 = bx * 64;

    const int ar = tid >> 1, ac = (tid & 1) * 32;   // A stage: 2 thr/row, 32 elems
    const int br = tid >> 2, bc = (tid & 3) * 16;   // W stage: 4 thr/row, 16 elems

    f32x4 acc[4][2] = {};
    bf16x8 sa[4], sw[2];

    auto LOAD = [&](int kt) {
        const int k0 = kt * 64;
        const unsigned short* Ap = Ab + (size_t)(m0 + ar)*K + k0 + ac;
        #pragma unroll
        for (int i = 0; i < 4; ++i)
            sa[i] = *(const bf16x8*)(Ap + i*8);
        const float* Wp = W + (size_t)(n0 + br)*K + k0 + bc;
        #pragma unroll
        for (int i = 0; i < 2; ++i)
            sw[i] = pack8(*(const float4*)(Wp + i*8), *(const float4*)(Wp + i*8 + 4));
    };
    auto STORE = [&]() {
        #pragma unroll
        for (int i = 0; i < 4; ++i) *(bf16x8*)&As[ar][ac + i*8] = sa[i];
        #pragma unroll
        for (int i = 0; i < 2; ++i) *(bf16x8*)&Bs[br][bc + i*8] = sw[i];
    };

    const int nk = K / 64;
    LOAD(0);
    for (int kt = 0; kt < nk; ++kt) {
        __syncthreads();
        STORE();
        __syncthreads();
        if (kt + 1 < nk) LOAD(kt + 1);
        #pragma unroll
        for (int ks = 0; ks < 2; ++ks) {
            bf16x8 bf0 = *(const bf16x8*)&Bs[wc*32 +  0 + lq][ks*32 + g*8];
            bf16x8 bf1 = *(const bf16x8*)&Bs[wc*32 + 16 + lq][ks*32 + g*8];
            #pragma unroll
            for (int i = 0; i < 4; ++i) {
                bf16x8 af = *(const bf16x8*)&As[wr*64 + i*16 + lq][ks*32 + g*8];
                acc[i][0] = __builtin_amdgcn_mfma_f32_16x16x32_bf16(af, bf0, acc[i][0], 0, 0, 0);
                acc[i][1] = __builtin_amdgcn_mfma_f32_16x16x32_bf16(af, bf1, acc[i][1], 0, 0, 0);
            }
        }
    }

    float bb[2];
    #pragma unroll
    for (int j = 0; j < 2; ++j) bb[j] = bias[n0 + wc*32 + j*16 + lq];

    #pragma unroll
    for (int i = 0; i < 4; ++i) {
        const int mb = m0 + wr*64 + i*16 + 4*g;
        #pragma unroll
        for (int j = 0; j < 2; ++j) {
            const int n = n0 + wc*32 + j*16 + lq;
            f32x4 v = acc[i][j];
            v[0] += bb[j]; v[1] += bb[j]; v[2] += bb[j]; v[3] += bb[j];
            if (mode == 0) {
                float* Cf = (float*)Cv;
                #pragma unroll
                for (int r = 0; r < 4; ++r) Cf[(size_t)(mb + r)*N + n] = v[r];
            } else if (mode == 1) {
                unsigned short* Cb = (unsigned short*)Cv;
                #pragma unroll
                for (int r = 0; r < 4; ++r) Cb[(size_t)(mb + r)*N + n] = f2bf(v[r]);
            } else if (mode == 3) {
                unsigned short* Cb = (unsigned short*)Cv;
                #pragma unroll
                for (int r = 0; r < 4; ++r) Cb[(size_t)(mb + r)*N + n] = f2bf(fmaxf(v[r], 0.f));
            } else {
                unsigned short* Cb = (unsigned short*)Cv;
                const int bI = mb / L, kk = mb % L;
                const int hh = n >> 5, d0 = n & 31;
                ushort4 pk;
                pk.x = f2bf(v[0]); pk.y = f2bf(v[1]); pk.z = f2bf(v[2]); pk.w = f2bf(v[3]);
                *(ushort4*)(Cb + ((size_t)(bI*NH + hh)*DH + d0)*L + kk) = pk;
            }
        }
    }
}

__global__ __launch_bounds__(256) void gemm_mfma(const unsigned short* __restrict__ A,
    const float* __restrict__ W, const float* __restrict__ bias,
    void* __restrict__ C, int M, int N, int K, int mode, int L)
{
    gemm_core(A, W, bias, C, M, N, K, mode, L, blockIdx.x, blockIdx.y);
}

// fused Q/K/V projections: blockIdx.z selects which
__global__ __launch_bounds__(256) void qkv_mfma(const unsigned short* __restrict__ Aq,
    const unsigned short* __restrict__ Akv,
    const float* __restrict__ Wq, const float* __restrict__ bq,
    const float* __restrict__ Wk, const float* __restrict__ bk,
    const float* __restrict__ Wv, const float* __restrict__ bv,
    void* __restrict__ qo, void* __restrict__ ko, void* __restrict__ vo,
    int Mq, int Mkv, int L)
{
    const int z = blockIdx.z;
    const unsigned short* A = (z == 0) ? Aq : Akv;
    const float* W = (z == 0) ? Wq : ((z == 1) ? Wk : Wv);
    const float* bb = (z == 0) ? bq : ((z == 1) ? bk : bv);
    void* C = (z == 0) ? qo : ((z == 1) ? ko : vo);
    const int M = (z == 0) ? Mq : Mkv;
    const int mode = (z == 2) ? 2 : 1;
    if ((int)blockIdx.y * 128 >= M) return;
    gemm_core(A, W, bb, C, M, HID, HID, mode, L, blockIdx.x, blockIdx.y);
}

// ---------------- fused MFMA attention (bf16 in/out, fp32 accum) ------------
__global__ __launch_bounds__(256) void attn_mfma(const unsigned short* __restrict__ Qb,
    const unsigned short* __restrict__ Kb, const unsigned short* __restrict__ VTb,
    unsigned short* __restrict__ O, int Lk)
{
    __shared__ __attribute__((aligned(16))) unsigned short Kl[64][40];
    __shared__ __attribute__((aligned(16))) unsigned short Vl[32][72];
    __shared__ __attribute__((aligned(16))) unsigned short Pl[4][16][40];
    const int b = blockIdx.z, h = blockIdx.y, qt = blockIdx.x;
    const int tid = threadIdx.x, wave = tid >> 6, lane = tid & 63;
    const int lq = lane & 15, g = lane >> 4;

    const unsigned short* qp = Qb + ((size_t)(b*NA + qt*64 + wave*16 + lq))*HID + h*DH + g*8;
    bf16x8 qf = *(const bf16x8*)qp;

    f32x4 o0 = {0.f,0.f,0.f,0.f}, o1 = {0.f,0.f,0.f,0.f};
    float m = -1e30f, l = 0.f;
    const float sc = 0.17677669529663687f;   // 1/sqrt(32)

    const unsigned short* Kg = Kb  + ((size_t)b*Lk)*HID + h*DH;
    const unsigned short* Vg = VTb + ((size_t)(b*NH + h))*DH*Lk;

    const int krow = tid >> 2, kseg = tid & 3;
    const int vrow = tid >> 3, vseg = tid & 7;

    for (int kt0 = 0; kt0 < Lk; kt0 += 64) {
        __syncthreads();
        *(bf16x8*)&Kl[krow][kseg*8] = *(const bf16x8*)(Kg + (size_t)(kt0 + krow)*HID + kseg*8);
        *(bf16x8*)&Vl[vrow][vseg*8] = *(const bf16x8*)(Vg + (size_t)vrow*Lk + kt0 + vseg*8);
        __syncthreads();

        f32x4 st[4];
        #pragma unroll
        for (int j = 0; j < 4; ++j) {
            bf16x8 kf = *(const bf16x8*)&Kl[j*16 + lq][g*8];
            f32x4 z = {0.f,0.f,0.f,0.f};
            st[j] = __builtin_amdgcn_mfma_f32_16x16x32_bf16(kf, qf, z, 0, 0, 0);
        }
        float tm = -1e30f;
        #pragma unroll
        for (int j = 0; j < 4; ++j) {
            #pragma unroll
            for (int r = 0; r < 4; ++r) { st[j][r] *= sc; tm = fmaxf(tm, st[j][r]); }
        }
        tm = fmaxf(tm, __shfl_xor(tm, 16));
        tm = fmaxf(tm, __shfl_xor(tm, 32));
        float mn = fmaxf(m, tm);
        float corr = __expf(m - mn);
        m = mn;
        float rs = 0.f;
        #pragma unroll
        for (int j = 0; j < 4; ++j) {
            float p0 = __expf(st[j][0] - mn), p1 = __expf(st[j][1] - mn);
            float p2 = __expf(st[j][2] - mn), p3 = __expf(st[j][3] - mn);
            rs += p0 + p1 + p2 + p3;
            ushort4 pk;
            pk.x = f2bf(p0); pk.y = f2bf(p1); pk.z = f2bf(p2); pk.w = f2bf(p3);
            *(ushort4*)&Pl[wave][lq][j*16 + g*4] = pk;
        }
        rs += __shfl_xor(rs, 16);
        rs += __shfl_xor(rs, 32);
        l = l * corr + rs;
        float c0 = __shfl(corr, 4*g + 0), c1 = __shfl(corr, 4*g + 1);
        float c2 = __shfl(corr, 4*g + 2), c3 = __shfl(corr, 4*g + 3);
        o0[0] *= c0; o0[1] *= c1; o0[2] *= c2; o0[3] *= c3;
        o1[0] *= c0; o1[1] *= c1; o1[2] *= c2; o1[3] *= c3;
        #pragma unroll
        for (int c = 0; c < 2; ++c) {
            bf16x8 pf = *(const bf16x8*)&Pl[wave][lq][c*32 + g*8];
            bf16x8 v0 = *(const bf16x8*)&Vl[lq][c*32 + g*8];
            bf16x8 v1 = *(const bf16x8*)&Vl[16 + lq][c*32 + g*8];
            o0 = __builtin_amdgcn_mfma_f32_16x16x32_bf16(pf, v0, o0, 0, 0, 0);
            o1 = __builtin_amdgcn_mfma_f32_16x16x32_bf16(pf, v1, o1, 0, 0, 0);
        }
    }
    float linv = 1.f / l;
    float i0 = __shfl(linv, 4*g + 0), i1 = __shfl(linv, 4*g + 1);
    float i2 = __shfl(linv, 4*g + 2), i3 = __shfl(linv, 4*g + 3);
    unsigned short* Op = O + ((size_t)(b*NA + qt*64 + wave*16))*HID + h*DH;
    float iv[4] = {i0, i1, i2, i3};
    #pragma unroll
    for (int r = 0; r < 4; ++r) {
        Op[(size_t)(4*g + r)*HID + lq]      = f2bf(o0[r] * iv[r]);
        Op[(size_t)(4*g + r)*HID + 16 + lq] = f2bf(o1[r] * iv[r]);
    }
}

// ---------------- residual add + LayerNorm (wave per row, dual output) ------
__global__ __launch_bounds__(256) void add_ln(float* __restrict__ x,
    const float* __restrict__ t, const float* __restrict__ g,
    const float* __restrict__ bt, unsigned short* __restrict__ xb)
{
    const int row = blockIdx.x*4 + (threadIdx.x >> 6);
    const int lane = threadIdx.x & 63;
    const size_t base = (size_t)row*HID + lane*4;
    float4 v = *(const float4*)(x + base);
    float4 tv = *(const float4*)(t + base);
    v.x += tv.x; v.y += tv.y; v.z += tv.z; v.w += tv.w;
    float s = v.x + v.y + v.z + v.w;
    #pragma unroll
    for (int o = 32; o > 0; o >>= 1) s += __shfl_xor(s, o);
    float mean = s * (1.f/256.f);
    float4 d = {v.x - mean, v.y - mean, v.z - mean, v.w - mean};
    float q2 = d.x*d.x + d.y*d.y + d.z*d.z + d.w*d.w;
    #pragma unroll
    for (int o = 32; o > 0; o >>= 1) q2 += __shfl_xor(q2, o);
    float rs = rsqrtf(q2*(1.f/256.f) + 1e-5f);
    float4 gv = *(const float4*)(g + lane*4);
    float4 bv = *(const float4*)(bt + lane*4);
    float4 ov;
    ov.x = d.x*rs*gv.x + bv.x; ov.y = d.y*rs*gv.y + bv.y;
    ov.z = d.z*rs*gv.z + bv.z; ov.w = d.w*rs*gv.w + bv.w;
    *(float4*)(x + base) = ov;
    ushort4 pk;
    pk.x = f2bf(ov.x); pk.y = f2bf(ov.y); pk.z = f2bf(ov.z); pk.w = f2bf(ov.w);
    *(ushort4*)(xb + base) = pk;
}

// ---------------- pooling: row norms (wave per row) -------------------------
__global__ __launch_bounds__(256) void norms_k(const float* __restrict__ x,
    float* __restrict__ nw)
{
    const int row = blockIdx.x*4 + (threadIdx.x >> 6);
    const int lane = threadIdx.x & 63;
    float4 v = *(const float4*)(x + (size_t)row*HID + lane*4);
    float s = v.x*v.x + v.y*v.y + v.z*v.z + v.w*v.w;
    #pragma unroll
    for (int o = 32; o > 0; o >>= 1) s += __shfl_xor(s, o);
    if (lane == 0) nw[row] = sqrtf(s);
}

// ---------------- pooling: softmax-weighted sum over rows -------------------
// grid (B_, 8): each block handles 32 h-columns of one batch.
__global__ __launch_bounds__(256) void pooled_k(const float* __restrict__ x,
    const float* __restrict__ nw, float* __restrict__ pooled)
{
    __shared__ float sw[NA];
    __shared__ float red[256];
    __shared__ float part[8][33];
    const int b = blockIdx.x, hc = blockIdx.y;
    const int tid = threadIdx.x;
    const float* nb = nw + (size_t)b*NA;
    float v0 = nb[tid], v1 = nb[tid + 256];
    red[tid] = fmaxf(v0, v1); __syncthreads();
    for (int s = 128; s > 0; s >>= 1) { if (tid < s) red[tid] = fmaxf(red[tid], red[tid+s]); __syncthreads(); }
    float mx = red[0]; __syncthreads();
    float e0 = __expf(v0 - mx), e1 = __expf(v1 - mx);
    sw[tid] = e0; sw[tid + 256] = e1;
    red[tid] = e0 + e1; __syncthreads();
    for (int s = 128; s > 0; s >>= 1) { if (tid < s) red[tid] += red[tid+s]; __syncthreads(); }
    float inv = 1.f / red[0];
    __syncthreads();
    const int ng = tid >> 5, col = tid & 31;
    const float* xp = x + (size_t)b*NA*HID + hc*32 + col;
    float acc = 0.f;
    for (int n = ng; n < NA; n += 8)
        acc += sw[n] * xp[(size_t)n*HID];
    part[ng][col] = acc;
    __syncthreads();
    if (tid < 32) {
        float s = 0.f;
        #pragma unroll
        for (int i = 0; i < 8; ++i) s += part[i][tid];
        pooled[(size_t)b*HID + hc*32 + tid] = s * inv;
    }
}

// ---------------- FC head ---------------------------------------------------
__global__ __launch_bounds__(256) void head_k(const float* __restrict__ pooled,
    const float* __restrict__ fc1w, const float* __restrict__ fc1b,
    const float* __restrict__ fc2w, const float* __restrict__ fc2b,
    float* __restrict__ out)
{
    __shared__ float p[HID];
    __shared__ float a1[HID];
    const int b = blockIdx.x, tid = threadIdx.x;
    p[tid] = pooled[(size_t)b*HID + tid];
    __syncthreads();
    float s1 = fc1b[tid];
    const float* w1 = fc1w + (size_t)tid*HID;
    for (int k2 = 0; k2 < HID; k2 += 4) {
        float4 w = *(const float4*)(w1 + k2);
        s1 += p[k2]*w.x + p[k2+1]*w.y + p[k2+2]*w.z + p[k2+3]*w.w;
    }
    a1[tid] = fmaxf(s1, 0.f);
    __syncthreads();
    if (tid < 2) {
        float s2 = fc2b[tid];
        const float* w2 = fc2w + (size_t)tid*HID;
        for (int k2 = 0; k2 < HID; ++k2) s2 += a1[k2] * w2[k2];
        out[b*2 + tid] = s2;
    }
}

// ---------------- launch ----------------------------------------------------
extern "C" void kernel_launch(void* const* d_in, const int* in_sizes, int n_in,
                              void* d_out, int out_size, void* d_ws, size_t ws_size,
                              hipStream_t stream)
{
    const float* trg  = (const float*)d_in[0];
    const float* src  = (const float*)d_in[1];
    const float* ft_w = (const float*)d_in[2];
    const float* ft_b = (const float*)d_in[3];
    const float* ln_g = (const float*)d_in[4];
    const float* ln_b = (const float*)d_in[5];
    const float* sa_wq = (const float*)d_in[6];  const float* sa_bq = (const float*)d_in[7];
    const float* sa_wk = (const float*)d_in[8];  const float* sa_bk = (const float*)d_in[9];
    const float* sa_wv = (const float*)d_in[10]; const float* sa_bv = (const float*)d_in[11];
    const float* sa_wf = (const float*)d_in[12]; const float* sa_bf = (const float*)d_in[13];
    const float* ea_wq = (const float*)d_in[14]; const float* ea_bq = (const float*)d_in[15];
    const float* ea_wk = (const float*)d_in[16]; const float* ea_bk = (const float*)d_in[17];
    const float* ea_wv = (const float*)d_in[18]; const float* ea_bv = (const float*)d_in[19];
    const float* ea_wf = (const float*)d_in[20]; const float* ea_bf = (const float*)d_in[21];
    const float* pf_w1 = (const float*)d_in[22]; const float* pf_b1 = (const float*)d_in[23];
    const float* pf_w2 = (const float*)d_in[24]; const float* pf_b2 = (const float*)d_in[25];
    const float* fc1w  = (const float*)d_in[26]; const float* fc1b  = (const float*)d_in[27];
    const float* fc2w  = (const float*)d_in[28]; const float* fc2b  = (const float*)d_in[29];
    float* out = (float*)d_out;

    const size_t NTOK = (size_t)B_*NA;    // 16384
    const size_t NSRC = (size_t)B_*NP;    // 32768
    float* ws = (float*)d_ws;
    float* x  = ws;                        // [NTOK,HID] fp32 master
    float* u  = x + NTOK*HID;              // [NTOK,HID] fp32 (proj/ffn2 out)
    float* nw = u + NTOK*HID;              // [NTOK] row norms
    float* pooled = nw + NTOK;             // [B_,HID]
    unsigned short* xb   = (unsigned short*)(pooled + B_*HID); // [NTOK,HID] bf16 shadow
    unsigned short* tb   = xb + NTOK*HID;                      // [NTOK,HID] bf16 attn-out
    unsigned short* srcb = tb + NTOK*HID;                      // [NSRC,HID] bf16
    unsigned short* qb   = srcb + NSRC*HID;                    // [NTOK,HID] bf16
    unsigned short* kb   = qb + NTOK*HID;                      // [NSRC,HID] bf16
    unsigned short* vTb  = kb + NSRC*HID;                      // [NSRC,HID] bf16 transposed
    unsigned short* hb   = qb;             // [NTOK,PF] bf16 aliases qb..vTb

    const int M = (int)NTOK;
    dim3 blk(256);

    ft_kernel<<<M/32, blk, 0, stream>>>(trg, ft_w, ft_b, x, xb);
    cvt_bf16<<<1024, blk, 0, stream>>>(src, srcb, (int)(NSRC*HID/8));

    for (int l = 0; l < 2; ++l) {
        const size_t wo = (size_t)l*HID*HID, bo = (size_t)l*HID;
        // ---- self attention ----
        qkv_mfma<<<dim3(HID/64, M/128, 3), blk, 0, stream>>>(xb, xb,
            sa_wq+wo, sa_bq+bo, sa_wk+wo, sa_bk+bo, sa_wv+wo, sa_bv+bo,
            qb, kb, vTb, M, M, NA);
        attn_mfma<<<dim3(NA/64, NH, B_), blk, 0, stream>>>(qb, kb, vTb, tb, NA);
        gemm_mfma<<<dim3(HID/64, M/128), blk, 0, stream>>>(tb, sa_wf+wo, sa_bf+bo, u, M, HID, HID, 0, 0);
        add_ln<<<M/4, blk, 0, stream>>>(x, u, ln_g+bo, ln_b+bo, xb);
        // ---- cross attention ----
        qkv_mfma<<<dim3(HID/64, (int)NSRC/128, 3), blk, 0, stream>>>(xb, srcb,
            ea_wq+wo, ea_bq+bo, ea_wk+wo, ea_bk+bo, ea_wv+wo, ea_bv+bo,
            qb, kb, vTb, M, (int)NSRC, NP);
        attn_mfma<<<dim3(NA/64, NH, B_), blk, 0, stream>>>(qb, kb, vTb, tb, NP);
        gemm_mfma<<<dim3(HID/64, M/128), blk, 0, stream>>>(tb, ea_wf+wo, ea_bf+bo, u, M, HID, HID, 0, 0);
        add_ln<<<M/4, blk, 0, stream>>>(x, u, ln_g+bo, ln_b+bo, xb);
        // ---- feed-forward ----
        gemm_mfma<<<dim3(PF/64, M/128), blk, 0, stream>>>(xb, pf_w1+(size_t)l*PF*HID, pf_b1+(size_t)l*PF, hb, M, PF, HID, 3, 0);
        gemm_mfma<<<dim3(HID/64, M/128), blk, 0, stream>>>(hb, pf_w2+(size_t)l*HID*PF, pf_b2+bo, u, M, HID, PF, 0, 0);
        add_ln<<<M/4, blk, 0, stream>>>(x, u, ln_g+bo, ln_b+bo, xb);
    }

    norms_k<<<M/4, blk, 0, stream>>>(x, nw);
    pooled_k<<<dim3(B_, 8), blk, 0, stream>>>(x, nw, pooled);
    head_k<<<B_, blk, 0, stream>>>(pooled, fc1w, fc1b, fc2w, fc2b, out);
}

// Round 5
// 508.791 us; speedup vs baseline: 6.4320x; 1.1792x over previous
//
#include <hip/hip_runtime.h>
#include <hip/hip_bf16.h>
#include <math.h>

#define B_   32
#define NA   512
#define NP   1024
#define HID  256
#define NH   8
#define DH   32
#define PF   1024

typedef short bf16x8 __attribute__((ext_vector_type(8)));
typedef float f32x4  __attribute__((ext_vector_type(4)));
typedef float f32x16 __attribute__((ext_vector_type(16)));

#define ZERO16 {0.f,0.f,0.f,0.f,0.f,0.f,0.f,0.f,0.f,0.f,0.f,0.f,0.f,0.f,0.f,0.f}

static __device__ inline unsigned short f2bf(float f) {
    __hip_bfloat16 h = __float2bfloat16(f);   // RNE; pairs fuse to v_cvt_pk_bf16_f32
    unsigned short u;
    __builtin_memcpy(&u, &h, 2);
    return u;
}
static __device__ inline bf16x8 pack8(float4 a, float4 b) {
    bf16x8 r;
    r[0] = (short)f2bf(a.x); r[1] = (short)f2bf(a.y);
    r[2] = (short)f2bf(a.z); r[3] = (short)f2bf(a.w);
    r[4] = (short)f2bf(b.x); r[5] = (short)f2bf(b.y);
    r[6] = (short)f2bf(b.z); r[7] = (short)f2bf(b.w);
    return r;
}

// ---------------- feature transform: x = trg @ ft_w.T + ft_b (fp32 + bf16) --
__global__ __launch_bounds__(256) void ft_kernel(const float* __restrict__ trg,
    const float* __restrict__ w, const float* __restrict__ b,
    float* __restrict__ out, unsigned short* __restrict__ outb)
{
    __shared__ float Ws[256][35];
    int tid = threadIdx.x;
    for (int k = 0; k < 34; ++k) Ws[tid][k] = w[tid*34 + k];
    float bias = b[tid];
    __syncthreads();
    int m0 = blockIdx.x * 32;
    for (int r = 0; r < 32; ++r) {
        int m = m0 + r;
        const float* tr = trg + (size_t)m*34;
        float acc = bias;
        #pragma unroll
        for (int k = 0; k < 34; ++k) acc += tr[k] * Ws[tid][k];
        out [(size_t)m*HID + tid] = acc;
        outb[(size_t)m*HID + tid] = f2bf(acc);
    }
}

// ---------------- fp32 -> bf16 bulk convert ---------------------------------
__global__ __launch_bounds__(256) void cvt_bf16(const float* __restrict__ in,
    unsigned short* __restrict__ outb, int n8)
{
    int i = blockIdx.x*256 + threadIdx.x;
    int stride = gridDim.x*256;
    for (; i < n8; i += stride) {
        float4 a = *(const float4*)(in + (size_t)i*8);
        float4 b = *(const float4*)(in + (size_t)i*8 + 4);
        *(bf16x8*)(outb + (size_t)i*8) = pack8(a, b);
    }
}

// ---------------- weight pre-convert (10 tensors, one launch) ---------------
__global__ __launch_bounds__(256) void cvt_w(
    const float* __restrict__ s0, const float* __restrict__ s1,
    const float* __restrict__ s2, const float* __restrict__ s3,
    const float* __restrict__ s4, const float* __restrict__ s5,
    const float* __restrict__ s6, const float* __restrict__ s7,
    const float* __restrict__ s8, const float* __restrict__ s9,
    unsigned short* __restrict__ dst)
{
    const int z = blockIdx.z;
    const float* src;
    switch (z) {
        case 0: src = s0; break; case 1: src = s1; break;
        case 2: src = s2; break; case 3: src = s3; break;
        case 4: src = s4; break; case 5: src = s5; break;
        case 6: src = s6; break; case 7: src = s7; break;
        case 8: src = s8; break; default: src = s9; break;
    }
    const int n8 = (z < 8) ? 16384 : 65536;
    const size_t off = (z < 8) ? (size_t)z*131072 : (1048576u + (size_t)(z-8)*524288);
    unsigned short* o = dst + off;
    int i = blockIdx.x*256 + threadIdx.x;
    const int stride = gridDim.x*256;
    for (; i < n8; i += stride) {
        float4 a = *(const float4*)(src + (size_t)i*8);
        float4 b = *(const float4*)(src + (size_t)i*8 + 4);
        *(bf16x8*)(o + (size_t)i*8) = pack8(a, b);
    }
}

// ---------------- bf16 MFMA GEMM core: C[M,N] = A[M,K] @ W[N,K]^T + bias ----
// A, W bf16. mode: 0 fp32 out; 1 bf16 out; 2 bf16 out per-head transposed
//       VT[((bI*NH+h)*DH+d)*L + k]; 3 bf16 out + relu.
static __device__ inline void gemm_core(const unsigned short* __restrict__ Ab,
    const unsigned short* __restrict__ Wb, const float* __restrict__ bias,
    void* __restrict__ Cv, int M, int N, int K, int mode, int L, float oscale,
    int bx, int by)
{
    __shared__ __attribute__((aligned(16))) unsigned short As[128][72]; // 144B rows
    __shared__ __attribute__((aligned(16))) unsigned short Bs[64][72];
    const int tid = threadIdx.x;
    const int wave = tid >> 6, lane = tid & 63, lq = lane & 15, g = lane >> 4;
    const int wr = wave >> 1, wc = wave & 1;
    const int m0 = by * 128, n0 = bx * 64;

    const int ar = tid >> 1, ac = (tid & 1) * 32;   // A stage: 2 thr/row, 32 elems
    const int br = tid >> 2, bc = (tid & 3) * 16;   // W stage: 4 thr/row, 16 elems

    f32x4 acc[4][2] = {};
    bf16x8 sa[4], sw[2];

    auto LOAD = [&](int kt) {
        const int k0 = kt * 64;
        const unsigned short* Ap = Ab + (size_t)(m0 + ar)*K + k0 + ac;
        #pragma unroll
        for (int i = 0; i < 4; ++i)
            sa[i] = *(const bf16x8*)(Ap + i*8);
        const unsigned short* Wp = Wb + (size_t)(n0 + br)*K + k0 + bc;
        #pragma unroll
        for (int i = 0; i < 2; ++i)
            sw[i] = *(const bf16x8*)(Wp + i*8);
    };
    auto STORE = [&]() {
        #pragma unroll
        for (int i = 0; i < 4; ++i) *(bf16x8*)&As[ar][ac + i*8] = sa[i];
        #pragma unroll
        for (int i = 0; i < 2; ++i) *(bf16x8*)&Bs[br][bc + i*8] = sw[i];
    };

    const int nk = K / 64;
    LOAD(0);
    for (int kt = 0; kt < nk; ++kt) {
        __syncthreads();
        STORE();
        __syncthreads();
        if (kt + 1 < nk) LOAD(kt + 1);
        #pragma unroll
        for (int ks = 0; ks < 2; ++ks) {
            bf16x8 bf0 = *(const bf16x8*)&Bs[wc*32 +  0 + lq][ks*32 + g*8];
            bf16x8 bf1 = *(const bf16x8*)&Bs[wc*32 + 16 + lq][ks*32 + g*8];
            #pragma unroll
            for (int i = 0; i < 4; ++i) {
                bf16x8 af = *(const bf16x8*)&As[wr*64 + i*16 + lq][ks*32 + g*8];
                acc[i][0] = __builtin_amdgcn_mfma_f32_16x16x32_bf16(af, bf0, acc[i][0], 0, 0, 0);
                acc[i][1] = __builtin_amdgcn_mfma_f32_16x16x32_bf16(af, bf1, acc[i][1], 0, 0, 0);
            }
        }
    }

    float bb[2];
    #pragma unroll
    for (int j = 0; j < 2; ++j) bb[j] = bias[n0 + wc*32 + j*16 + lq];

    #pragma unroll
    for (int i = 0; i < 4; ++i) {
        const int mb = m0 + wr*64 + i*16 + 4*g;
        #pragma unroll
        for (int j = 0; j < 2; ++j) {
            const int n = n0 + wc*32 + j*16 + lq;
            f32x4 v = acc[i][j];
            #pragma unroll
            for (int r = 0; r < 4; ++r) v[r] = (v[r] + bb[j]) * oscale;
            if (mode == 0) {
                float* Cf = (float*)Cv;
                #pragma unroll
                for (int r = 0; r < 4; ++r) Cf[(size_t)(mb + r)*N + n] = v[r];
            } else if (mode == 1) {
                unsigned short* Cb = (unsigned short*)Cv;
                #pragma unroll
                for (int r = 0; r < 4; ++r) Cb[(size_t)(mb + r)*N + n] = f2bf(v[r]);
            } else if (mode == 3) {
                unsigned short* Cb = (unsigned short*)Cv;
                #pragma unroll
                for (int r = 0; r < 4; ++r) Cb[(size_t)(mb + r)*N + n] = f2bf(fmaxf(v[r], 0.f));
            } else {
                unsigned short* Cb = (unsigned short*)Cv;
                const int bI = mb / L, kk = mb % L;
                const int hh = n >> 5, d0 = n & 31;
                ushort4 pk;
                pk.x = f2bf(v[0]); pk.y = f2bf(v[1]); pk.z = f2bf(v[2]); pk.w = f2bf(v[3]);
                *(ushort4*)(Cb + ((size_t)(bI*NH + hh)*DH + d0)*L + kk) = pk;
            }
        }
    }
}

__global__ __launch_bounds__(256) void gemm_mfma(const unsigned short* __restrict__ A,
    const unsigned short* __restrict__ W, const float* __restrict__ bias,
    void* __restrict__ C, int M, int N, int K, int mode, int L)
{
    gemm_core(A, W, bias, C, M, N, K, mode, L, 1.f, blockIdx.x, blockIdx.y);
}

// fused Q/K/V projections: blockIdx.z selects which. Q output pre-scaled.
__global__ __launch_bounds__(256) void qkv_mfma(const unsigned short* __restrict__ Aq,
    const unsigned short* __restrict__ Akv,
    const unsigned short* __restrict__ Wq, const float* __restrict__ bq,
    const unsigned short* __restrict__ Wk, const float* __restrict__ bk,
    const unsigned short* __restrict__ Wv, const float* __restrict__ bv,
    void* __restrict__ qo, void* __restrict__ ko, void* __restrict__ vo,
    int Mq, int Mkv, int L)
{
    const int z = blockIdx.z;
    const unsigned short* A = (z == 0) ? Aq : Akv;
    const unsigned short* W = (z == 0) ? Wq : ((z == 1) ? Wk : Wv);
    const float* bb = (z == 0) ? bq : ((z == 1) ? bk : bv);
    void* C = (z == 0) ? qo : ((z == 1) ? ko : vo);
    const int M = (z == 0) ? Mq : Mkv;
    const int mode = (z == 2) ? 2 : 1;
    const float sc = (z == 0) ? 0.17677669529663687f : 1.f;   // 1/sqrt(32)
    if ((int)blockIdx.y * 128 >= M) return;
    gemm_core(A, W, bb, C, M, HID, HID, mode, L, sc, blockIdx.x, blockIdx.y);
}

// ---------------- fused MFMA attention v2 (32x32x16, max-free softmax) ------
// grid (NA/128, NH, B_). Block = 4 waves; wave w owns q-rows [qt*128+w*32, +32).
__global__ __launch_bounds__(256) void attn_mfma(const unsigned short* __restrict__ Qb,
    const unsigned short* __restrict__ Kb, const unsigned short* __restrict__ VTb,
    unsigned short* __restrict__ O, int Lk)
{
    __shared__ __attribute__((aligned(16))) unsigned short Kl[64][40];    // 80B rows
    __shared__ __attribute__((aligned(16))) unsigned short Vl[32][72];    // 144B rows (d-major)
    __shared__ __attribute__((aligned(16))) unsigned short Pl[4][32][72]; // per-wave P[q][k]
    __shared__ __attribute__((aligned(16))) float Ll[4][32];
    const int b = blockIdx.z, h = blockIdx.y, qt = blockIdx.x;
    const int tid = threadIdx.x, w = tid >> 6, lane = tid & 63;
    const int q32 = lane & 31, hi = lane >> 5;

    // hoisted Q fragments (B-operand): lane -> (q = q32, d = c*16 + hi*8 ..+7)
    const unsigned short* qp = Qb + ((size_t)(b*NA + qt*128 + w*32 + q32))*HID + h*DH + hi*8;
    bf16x8 qf0 = *(const bf16x8*)qp;
    bf16x8 qf1 = *(const bf16x8*)(qp + 16);

    const unsigned short* Kg = Kb  + ((size_t)b*Lk)*HID + h*DH;
    const unsigned short* Vg = VTb + ((size_t)(b*NH + h))*DH*Lk;

    const int kr = tid >> 2, kc = (tid & 3) * 8;   // K stage: 4 thr/row
    const int vr = tid >> 3, vc = (tid & 7) * 8;   // V stage: 8 thr/row

    f32x16 o = ZERO16;
    float lacc = 0.f;

    bf16x8 kreg, vreg;
    auto LOADKV = [&](int kt0) {
        kreg = *(const bf16x8*)(Kg + (size_t)(kt0 + kr)*HID + kc);
        vreg = *(const bf16x8*)(Vg + (size_t)vr*Lk + kt0 + vc);
    };

    LOADKV(0);
    for (int kt0 = 0; kt0 < Lk; kt0 += 64) {
        __syncthreads();
        *(bf16x8*)&Kl[kr][kc] = kreg;
        *(bf16x8*)&Vl[vr][vc] = vreg;
        __syncthreads();
        if (kt0 + 64 < Lk) LOADKV(kt0 + 64);

        // S^T tiles: st{t}[reg] = S[q=q32][k = kt0 + 32t + (reg&3)+8*(reg>>2)+4*hi]
        f32x16 st0 = ZERO16, st1 = ZERO16;
        {
            bf16x8 k00 = *(const bf16x8*)&Kl[q32     ][hi*8];
            bf16x8 k01 = *(const bf16x8*)&Kl[q32     ][16 + hi*8];
            bf16x8 k10 = *(const bf16x8*)&Kl[32 + q32][hi*8];
            bf16x8 k11 = *(const bf16x8*)&Kl[32 + q32][16 + hi*8];
            st0 = __builtin_amdgcn_mfma_f32_32x32x16_bf16(k00, qf0, st0, 0, 0, 0);
            st0 = __builtin_amdgcn_mfma_f32_32x32x16_bf16(k01, qf1, st0, 0, 0, 0);
            st1 = __builtin_amdgcn_mfma_f32_32x32x16_bf16(k10, qf0, st1, 0, 0, 0);
            st1 = __builtin_amdgcn_mfma_f32_32x32x16_bf16(k11, qf1, st1, 0, 0, 0);
        }
        // max-free softmax numerator: p = exp(s); per-lane partial row sum
        float lp = 0.f;
        #pragma unroll
        for (int t = 0; t < 2; ++t) {
            const f32x16& stt = t ? st1 : st0;
            #pragma unroll
            for (int jg = 0; jg < 4; ++jg) {
                float p0 = __expf(stt[jg*4+0]), p1 = __expf(stt[jg*4+1]);
                float p2 = __expf(stt[jg*4+2]), p3 = __expf(stt[jg*4+3]);
                lp += p0 + p1 + p2 + p3;
                ushort4 pk;
                pk.x = f2bf(p0); pk.y = f2bf(p1); pk.z = f2bf(p2); pk.w = f2bf(p3);
                *(ushort4*)&Pl[w][q32][t*32 + jg*8 + hi*4] = pk;
            }
        }
        lacc += lp;
        // PV: O[q][d] += P[q][k] V[k][d]   (A=P from Pl, B=VT from Vl)
        #pragma unroll
        for (int c = 0; c < 4; ++c) {
            bf16x8 pf = *(const bf16x8*)&Pl[w][q32][c*16 + hi*8];
            bf16x8 vf = *(const bf16x8*)&Vl[q32][c*16 + hi*8];
            o = __builtin_amdgcn_mfma_f32_32x32x16_bf16(pf, vf, o, 0, 0, 0);
        }
    }

    float lt = lacc + __shfl_xor(lacc, 32);
    float linv = 1.f / lt;
    if (hi == 0) Ll[w][q32] = linv;
    f32x4 li[4];
    #pragma unroll
    for (int jg = 0; jg < 4; ++jg) li[jg] = *(const f32x4*)&Ll[w][jg*8 + hi*4];

    unsigned short* Op = O + ((size_t)(b*NA + qt*128 + w*32))*HID + h*DH + q32;
    #pragma unroll
    for (int jg = 0; jg < 4; ++jg) {
        #pragma unroll
        for (int r2 = 0; r2 < 4; ++r2) {
            const int q = jg*8 + hi*4 + r2;
            Op[(size_t)q*HID] = f2bf(o[jg*4 + r2] * li[jg][r2]);
            (void)0;
        }
    }
}

// ---------------- residual add + LayerNorm (wave per row, dual output) ------
__global__ __launch_bounds__(256) void add_ln(float* __restrict__ x,
    const float* __restrict__ t, const float* __restrict__ g,
    const float* __restrict__ bt, unsigned short* __restrict__ xb)
{
    const int row = blockIdx.x*4 + (threadIdx.x >> 6);
    const int lane = threadIdx.x & 63;
    const size_t base = (size_t)row*HID + lane*4;
    float4 v = *(const float4*)(x + base);
    float4 tv = *(const float4*)(t + base);
    v.x += tv.x; v.y += tv.y; v.z += tv.z; v.w += tv.w;
    float s = v.x + v.y + v.z + v.w;
    #pragma unroll
    for (int o = 32; o > 0; o >>= 1) s += __shfl_xor(s, o);
    float mean = s * (1.f/256.f);
    float4 d = {v.x - mean, v.y - mean, v.z - mean, v.w - mean};
    float q2 = d.x*d.x + d.y*d.y + d.z*d.z + d.w*d.w;
    #pragma unroll
    for (int o = 32; o > 0; o >>= 1) q2 += __shfl_xor(q2, o);
    float rs = rsqrtf(q2*(1.f/256.f) + 1e-5f);
    float4 gv = *(const float4*)(g + lane*4);
    float4 bv = *(const float4*)(bt + lane*4);
    float4 ov;
    ov.x = d.x*rs*gv.x + bv.x; ov.y = d.y*rs*gv.y + bv.y;
    ov.z = d.z*rs*gv.z + bv.z; ov.w = d.w*rs*gv.w + bv.w;
    *(float4*)(x + base) = ov;
    ushort4 pk;
    pk.x = f2bf(ov.x); pk.y = f2bf(ov.y); pk.z = f2bf(ov.z); pk.w = f2bf(ov.w);
    *(ushort4*)(xb + base) = pk;
}

// ---------------- pooling: row norms (wave per row) -------------------------
__global__ __launch_bounds__(256) void norms_k(const float* __restrict__ x,
    float* __restrict__ nw)
{
    const int row = blockIdx.x*4 + (threadIdx.x >> 6);
    const int lane = threadIdx.x & 63;
    float4 v = *(const float4*)(x + (size_t)row*HID + lane*4);
    float s = v.x*v.x + v.y*v.y + v.z*v.z + v.w*v.w;
    #pragma unroll
    for (int o = 32; o > 0; o >>= 1) s += __shfl_xor(s, o);
    if (lane == 0) nw[row] = sqrtf(s);
}

// ---------------- pooling: softmax-weighted sum over rows -------------------
__global__ __launch_bounds__(256) void pooled_k(const float* __restrict__ x,
    const float* __restrict__ nw, float* __restrict__ pooled)
{
    __shared__ float sw[NA];
    __shared__ float red[256];
    __shared__ float part[8][33];
    const int b = blockIdx.x, hc = blockIdx.y;
    const int tid = threadIdx.x;
    const float* nb = nw + (size_t)b*NA;
    float v0 = nb[tid], v1 = nb[tid + 256];
    red[tid] = fmaxf(v0, v1); __syncthreads();
    for (int s = 128; s > 0; s >>= 1) { if (tid < s) red[tid] = fmaxf(red[tid], red[tid+s]); __syncthreads(); }
    float mx = red[0]; __syncthreads();
    float e0 = __expf(v0 - mx), e1 = __expf(v1 - mx);
    sw[tid] = e0; sw[tid + 256] = e1;
    red[tid] = e0 + e1; __syncthreads();
    for (int s = 128; s > 0; s >>= 1) { if (tid < s) red[tid] += red[tid+s]; __syncthreads(); }
    float inv = 1.f / red[0];
    __syncthreads();
    const int ng = tid >> 5, col = tid & 31;
    const float* xp = x + (size_t)b*NA*HID + hc*32 + col;
    float acc = 0.f;
    for (int n = ng; n < NA; n += 8)
        acc += sw[n] * xp[(size_t)n*HID];
    part[ng][col] = acc;
    __syncthreads();
    if (tid < 32) {
        float s = 0.f;
        #pragma unroll
        for (int i = 0; i < 8; ++i) s += part[i][tid];
        pooled[(size_t)b*HID + hc*32 + tid] = s * inv;
    }
}

// ---------------- FC head ---------------------------------------------------
__global__ __launch_bounds__(256) void head_k(const float* __restrict__ pooled,
    const float* __restrict__ fc1w, const float* __restrict__ fc1b,
    const float* __restrict__ fc2w, const float* __restrict__ fc2b,
    float* __restrict__ out)
{
    __shared__ float p[HID];
    __shared__ float a1[HID];
    const int b = blockIdx.x, tid = threadIdx.x;
    p[tid] = pooled[(size_t)b*HID + tid];
    __syncthreads();
    float s1 = fc1b[tid];
    const float* w1 = fc1w + (size_t)tid*HID;
    for (int k2 = 0; k2 < HID; k2 += 4) {
        float4 w = *(const float4*)(w1 + k2);
        s1 += p[k2]*w.x + p[k2+1]*w.y + p[k2+2]*w.z + p[k2+3]*w.w;
    }
    a1[tid] = fmaxf(s1, 0.f);
    __syncthreads();
    if (tid < 2) {
        float s2 = fc2b[tid];
        const float* w2 = fc2w + (size_t)tid*HID;
        for (int k2 = 0; k2 < HID; ++k2) s2 += a1[k2] * w2[k2];
        out[b*2 + tid] = s2;
    }
}

// ---------------- launch ----------------------------------------------------
extern "C" void kernel_launch(void* const* d_in, const int* in_sizes, int n_in,
                              void* d_out, int out_size, void* d_ws, size_t ws_size,
                              hipStream_t stream)
{
    const float* trg  = (const float*)d_in[0];
    const float* src  = (const float*)d_in[1];
    const float* ft_w = (const float*)d_in[2];
    const float* ft_b = (const float*)d_in[3];
    const float* ln_g = (const float*)d_in[4];
    const float* ln_b = (const float*)d_in[5];
    const float* sa_wq = (const float*)d_in[6];  const float* sa_bq = (const float*)d_in[7];
    const float* sa_wk = (const float*)d_in[8];  const float* sa_bk = (const float*)d_in[9];
    const float* sa_wv = (const float*)d_in[10]; const float* sa_bv = (const float*)d_in[11];
    const float* sa_wf = (const float*)d_in[12]; const float* sa_bf = (const float*)d_in[13];
    const float* ea_wq = (const float*)d_in[14]; const float* ea_bq = (const float*)d_in[15];
    const float* ea_wk = (const float*)d_in[16]; const float* ea_bk = (const float*)d_in[17];
    const float* ea_wv = (const float*)d_in[18]; const float* ea_bv = (const float*)d_in[19];
    const float* ea_wf = (const float*)d_in[20]; const float* ea_bf = (const float*)d_in[21];
    const float* pf_w1 = (const float*)d_in[22]; const float* pf_b1 = (const float*)d_in[23];
    const float* pf_w2 = (const float*)d_in[24]; const float* pf_b2 = (const float*)d_in[25];
    const float* fc1w  = (const float*)d_in[26]; const float* fc1b  = (const float*)d_in[27];
    const float* fc2w  = (const float*)d_in[28]; const float* fc2b  = (const float*)d_in[29];
    float* out = (float*)d_out;

    const size_t NTOK = (size_t)B_*NA;    // 16384
    const size_t NSRC = (size_t)B_*NP;    // 32768
    float* ws = (float*)d_ws;
    float* x  = ws;                        // [NTOK,HID] fp32 master
    float* u  = x + NTOK*HID;              // [NTOK,HID] fp32 (proj/ffn2 out)
    float* nw = u + NTOK*HID;              // [NTOK] row norms
    float* pooled = nw + NTOK;             // [B_,HID]
    unsigned short* xb   = (unsigned short*)(pooled + B_*HID); // [NTOK,HID] bf16 shadow
    unsigned short* tb   = xb + NTOK*HID;                      // [NTOK,HID] bf16 attn-out
    unsigned short* srcb = tb + NTOK*HID;                      // [NSRC,HID] bf16
    unsigned short* qb   = srcb + NSRC*HID;                    // [NTOK,HID] bf16
    unsigned short* kb   = qb + NTOK*HID;                      // [NSRC,HID] bf16
    unsigned short* vTb  = kb + NSRC*HID;                      // [NSRC,HID] bf16 transposed
    unsigned short* wb   = vTb + NSRC*HID;                     // 2097152 bf16 weights
    unsigned short* hb   = qb;             // [NTOK,PF] bf16 aliases qb..vTb

    // pre-converted weight pointers
    unsigned short* saq_b = wb;
    unsigned short* sak_b = wb +  131072;
    unsigned short* sav_b = wb +  262144;
    unsigned short* saf_b = wb +  393216;
    unsigned short* eaq_b = wb +  524288;
    unsigned short* eak_b = wb +  655360;
    unsigned short* eav_b = wb +  786432;
    unsigned short* eaf_b = wb +  917504;
    unsigned short* pw1_b = wb + 1048576;
    unsigned short* pw2_b = wb + 1572864;

    const int M = (int)NTOK;
    dim3 blk(256);

    cvt_w<<<dim3(64, 1, 10), blk, 0, stream>>>(sa_wq, sa_wk, sa_wv, sa_wf,
        ea_wq, ea_wk, ea_wv, ea_wf, pf_w1, pf_w2, wb);
    ft_kernel<<<M/32, blk, 0, stream>>>(trg, ft_w, ft_b, x, xb);
    cvt_bf16<<<1024, blk, 0, stream>>>(src, srcb, (int)(NSRC*HID/8));

    for (int l = 0; l < 2; ++l) {
        const size_t wo = (size_t)l*HID*HID, bo = (size_t)l*HID;
        // ---- self attention ----
        qkv_mfma<<<dim3(HID/64, M/128, 3), blk, 0, stream>>>(xb, xb,
            saq_b+wo, sa_bq+bo, sak_b+wo, sa_bk+bo, sav_b+wo, sa_bv+bo,
            qb, kb, vTb, M, M, NA);
        attn_mfma<<<dim3(NA/128, NH, B_), blk, 0, stream>>>(qb, kb, vTb, tb, NA);
        gemm_mfma<<<dim3(HID/64, M/128), blk, 0, stream>>>(tb, saf_b+wo, sa_bf+bo, u, M, HID, HID, 0, 0);
        add_ln<<<M/4, blk, 0, stream>>>(x, u, ln_g+bo, ln_b+bo, xb);
        // ---- cross attention ----
        qkv_mfma<<<dim3(HID/64, (int)NSRC/128, 3), blk, 0, stream>>>(xb, srcb,
            eaq_b+wo, ea_bq+bo, eak_b+wo, ea_bk+bo, eav_b+wo, ea_bv+bo,
            qb, kb, vTb, M, (int)NSRC, NP);
        attn_mfma<<<dim3(NA/128, NH, B_), blk, 0, stream>>>(qb, kb, vTb, tb, NP);
        gemm_mfma<<<dim3(HID/64, M/128), blk, 0, stream>>>(tb, eaf_b+wo, ea_bf+bo, u, M, HID, HID, 0, 0);
        add_ln<<<M/4, blk, 0, stream>>>(x, u, ln_g+bo, ln_b+bo, xb);
        // ---- feed-forward ----
        gemm_mfma<<<dim3(PF/64, M/128), blk, 0, stream>>>(xb, pw1_b+(size_t)l*PF*HID, pf_b1+(size_t)l*PF, hb, M, PF, HID, 3, 0);
        gemm_mfma<<<dim3(HID/64, M/128), blk, 0, stream>>>(hb, pw2_b+(size_t)l*HID*PF, pf_b2+bo, u, M, HID, PF, 0, 0);
        add_ln<<<M/4, blk, 0, stream>>>(x, u, ln_g+bo, ln_b+bo, xb);
    }

    norms_k<<<M/4, blk, 0, stream>>>(x, nw);
    pooled_k<<<dim3(B_, 8), blk, 0, stream>>>(x, nw, pooled);
    head_k<<<B_, blk, 0, stream>>>(pooled, fc1w, fc1b, fc2w, fc2b, out);
}